// Round 1
// baseline (786.749 us; speedup 1.0000x reference)
//
#include <hip/hip_runtime.h>
#include <cstdint>

typedef unsigned short u16;
typedef __attribute__((ext_vector_type(8))) short short8;
typedef __attribute__((ext_vector_type(4))) float f32x4;

#define D_MODEL 2048
#define NHEAD   16
#define DK      128
#define SEQQ    2048
#define BATCH   2
#define MTOT    (BATCH*SEQQ)   // 4096

__device__ __forceinline__ u16 f2b(float f) {
  union { float f; uint32_t u; } c; c.f = f;
  uint32_t u = c.u;
  u += 0x7fffu + ((u >> 16) & 1u);
  return (u16)(u >> 16);
}
__device__ __forceinline__ float b2f(u16 h) {
  union { uint32_t u; float f; } c; c.u = ((uint32_t)h) << 16;
  return c.f;
}

__device__ __forceinline__ void gload_lds16(const void* g, void* l) {
  __builtin_amdgcn_global_load_lds(
      (const __attribute__((address_space(1))) void*)(uintptr_t)g,
      (__attribute__((address_space(3))) void*)(uint32_t)(uintptr_t)l,
      16, 0, 0);
}

// ---------------- f32 -> bf16 convert (vector 4) ----------------
__global__ __launch_bounds__(256) void cvt_bf16(const float* __restrict__ src,
                                                u16* __restrict__ dst, int n4) {
  int i = blockIdx.x * 256 + threadIdx.x;
  if (i >= n4) return;
  float4 v = ((const float4*)src)[i];
  union { u16 s[4]; uint64_t q; } o;
  o.s[0] = f2b(v.x); o.s[1] = f2b(v.y); o.s[2] = f2b(v.z); o.s[3] = f2b(v.w);
  ((uint64_t*)dst)[i] = o.q;
}

// ---------------- GEMM: C[M,N] = A[M,K] * B[N,K]^T (bf16 in, bf16/f32 out) ----------------
// 128x128 tile, BK=32, 256 threads = 4 waves (2x2), each wave 64x64 via 4x4 16x16x32 MFMA.
template<int F32OUT>
__global__ __launch_bounds__(256) void gemm_bt(const u16* __restrict__ A,
                                               const u16* __restrict__ B,
                                               void* __restrict__ Cout,
                                               int M, int N, int K) {
  __shared__ __align__(16) u16 As[128*32];
  __shared__ __align__(16) u16 Bs[128*32];
  const int tid  = threadIdx.x;
  const int lane = tid & 63;
  const int wave = tid >> 6;
  const int l15 = lane & 15, l4 = lane >> 4;
  const int m0 = blockIdx.y * 128, n0 = blockIdx.x * 128;
  const int wm = (wave >> 1) * 64, wn = (wave & 1) * 64;
  const int srow = tid >> 2;            // 0..63
  const int scol = (tid & 3) * 8;       // 0,8,16,24
  const u16* Ag = A + (size_t)(m0 + srow) * K + scol;
  const u16* Bg = B + (size_t)(n0 + srow) * K + scol;
  u16* al = As + (tid >> 6) * 512;      // wave-uniform LDS base
  u16* bl = Bs + (tid >> 6) * 512;

  f32x4 acc[4][4] = {};
  const int nkt = K / 32;
  for (int kt = 0; kt < nkt; ++kt) {
    __syncthreads();
    const u16* a0 = Ag + kt * 32;
    const u16* b0 = Bg + kt * 32;
    gload_lds16(a0,                  al);
    gload_lds16(a0 + (size_t)64 * K, al + 2048);
    gload_lds16(b0,                  bl);
    gload_lds16(b0 + (size_t)64 * K, bl + 2048);
    __syncthreads();   // drains vmcnt before any wave reads LDS
    short8 af[4], bfr[4];
#pragma unroll
    for (int m = 0; m < 4; ++m)
      af[m] = *(const short8*)&As[(wm + m*16 + l15)*32 + l4*8];
#pragma unroll
    for (int n = 0; n < 4; ++n)
      bfr[n] = *(const short8*)&Bs[(wn + n*16 + l15)*32 + l4*8];
#pragma unroll
    for (int m = 0; m < 4; ++m)
#pragma unroll
      for (int n = 0; n < 4; ++n)
        acc[m][n] = __builtin_amdgcn_mfma_f32_16x16x32_bf16(af[m], bfr[n], acc[m][n], 0, 0, 0);
  }
#pragma unroll
  for (int m = 0; m < 4; ++m) {
    const int row = m0 + wm + m*16 + l4*4;
#pragma unroll
    for (int n = 0; n < 4; ++n) {
      const int col = n0 + wn + n*16 + l15;
#pragma unroll
      for (int r = 0; r < 4; ++r) {
        if (F32OUT)
          ((float*)Cout)[(size_t)(row + r) * N + col] = acc[m][n][r];
        else
          ((u16*)Cout)[(size_t)(row + r) * N + col] = f2b(acc[m][n][r]);
      }
    }
  }
}

// ---------------- RoPE in-place on [MTOT][D_MODEL] bf16 ----------------
__global__ __launch_bounds__(256) void rope_k(u16* __restrict__ X, const int* __restrict__ pos) {
  int p = blockIdx.x * 256 + threadIdx.x;       // pair index, < MTOT*1024
  int m = p >> 10, j2 = p & 1023;
  int h = j2 >> 6, j = j2 & 63;
  int s = m & (SEQQ - 1);
  float fp = (float)pos[s];
  // freq = 10000^(-j/64) = 2^(-j * log2(10000)/64)
  float freq = exp2f((float)j * -0.20762050593046014f);
  float ang = fp * freq;
  float sn, cs;
  sincosf(ang, &sn, &cs);
  u16* px = X + (size_t)m * D_MODEL + h * DK + 2 * j;
  uint32_t pair = *(uint32_t*)px;
  float x1 = b2f((u16)(pair & 0xffff)), x2 = b2f((u16)(pair >> 16));
  u16 r1 = f2b(x1 * cs - x2 * sn);
  u16 r2 = f2b(x1 * sn + x2 * cs);
  *(uint32_t*)px = (uint32_t)r1 | ((uint32_t)r2 << 16);
}

// ---------------- V transpose: [b,s,h,d] -> [bh, d, s] ----------------
__global__ __launch_bounds__(256) void transpose_v(const u16* __restrict__ V, u16* __restrict__ Vt) {
  __shared__ u16 t[32][33];
  const int bh = blockIdx.z;
  const int d0 = blockIdx.y * 32;
  const int s0 = blockIdx.x * 32;
  const int b = bh >> 4, h = bh & 15;
  const int tid = threadIdx.x;
  for (int i = tid; i < 1024; i += 256) {
    int si = i >> 5, di = i & 31;
    t[si][di] = V[(size_t)(b * SEQQ + s0 + si) * D_MODEL + h * DK + d0 + di];
  }
  __syncthreads();
  for (int i = tid; i < 1024; i += 256) {
    int di = i >> 5, si = i & 31;
    Vt[((size_t)bh * DK + d0 + di) * SEQQ + s0 + si] = t[si][di];
  }
}

// ---------------- Flash attention (causal), bf16 MFMA ----------------
// grid (SEQQ/64, BATCH*NHEAD), 256 threads = 4 waves; wave w handles 16 queries.
__global__ __launch_bounds__(256) void attn_fwd(const u16* __restrict__ Q,
                                                const u16* __restrict__ Kg,
                                                const u16* __restrict__ Vt,
                                                u16* __restrict__ O) {
  __shared__ __align__(16) u16 Plds[4][16 * 72];   // per-wave P tile, padded stride 72
  const int tid = threadIdx.x, wave = tid >> 6, lane = tid & 63;
  const int l15 = lane & 15, l4 = lane >> 4;
  const int bx = blockIdx.x, bh = blockIdx.y;
  const int b = bh >> 4, h = bh & 15;
  const int q0 = bx * 64, qw = q0 + wave * 16;
  const float scale = 0.088388347648318447f;   // 1/sqrt(128)

  const u16* Qp = Q + (size_t)(b * SEQQ + qw + l15) * D_MODEL + h * DK + l4 * 8;
  short8 aq[4];
#pragma unroll
  for (int kc = 0; kc < 4; ++kc) aq[kc] = *(const short8*)(Qp + kc * 32);

  f32x4 facc[8] = {};
  float mrun[4], lrun[4];
#pragma unroll
  for (int r = 0; r < 4; ++r) { mrun[r] = -1e30f; lrun[r] = 0.f; }

  const u16* Kbase = Kg + (size_t)b * SEQQ * D_MODEL + h * DK;
  const u16* Vbase = Vt + (size_t)bh * DK * SEQQ;
  u16* Pl = Plds[wave];

  for (int kt = 0; kt <= bx; ++kt) {
    const int k0 = kt * 64;
    f32x4 sacc[4] = {};
#pragma unroll
    for (int ks = 0; ks < 4; ++ks) {
      const u16* Kp = Kbase + (size_t)(k0 + ks * 16 + l15) * D_MODEL + l4 * 8;
#pragma unroll
      for (int kc = 0; kc < 4; ++kc) {
        short8 bk = *(const short8*)(Kp + kc * 32);
        sacc[ks] = __builtin_amdgcn_mfma_f32_16x16x32_bf16(aq[kc], bk, sacc[ks], 0, 0, 0);
      }
    }
    float pmax[4] = {-1e30f, -1e30f, -1e30f, -1e30f};
    const bool diag = (kt == bx);
#pragma unroll
    for (int ks = 0; ks < 4; ++ks)
#pragma unroll
      for (int r = 0; r < 4; ++r) {
        float s = sacc[ks][r] * scale;
        if (diag && (k0 + ks * 16 + l15 > qw + l4 * 4 + r)) s = -1e30f;
        sacc[ks][r] = s;
        pmax[r] = fmaxf(pmax[r], s);
      }
#pragma unroll
    for (int off = 1; off < 16; off <<= 1)
#pragma unroll
      for (int r = 0; r < 4; ++r) pmax[r] = fmaxf(pmax[r], __shfl_xor(pmax[r], off, 64));
    float alpha[4], rsum[4];
#pragma unroll
    for (int r = 0; r < 4; ++r) {
      float mn = fmaxf(mrun[r], pmax[r]);
      alpha[r] = __expf(mrun[r] - mn);
      mrun[r] = mn;
      rsum[r] = 0.f;
    }
#pragma unroll
    for (int ks = 0; ks < 4; ++ks)
#pragma unroll
      for (int r = 0; r < 4; ++r) {
        float pv = __expf(sacc[ks][r] - mrun[r]);
        sacc[ks][r] = pv;
        rsum[r] += pv;
      }
#pragma unroll
    for (int off = 1; off < 16; off <<= 1)
#pragma unroll
      for (int r = 0; r < 4; ++r) rsum[r] += __shfl_xor(rsum[r], off, 64);
#pragma unroll
    for (int r = 0; r < 4; ++r) lrun[r] = lrun[r] * alpha[r] + rsum[r];
#pragma unroll
    for (int db = 0; db < 8; ++db)
#pragma unroll
      for (int r = 0; r < 4; ++r) facc[db][r] *= alpha[r];
    // P -> LDS (bf16) in A-fragment-friendly layout
#pragma unroll
    for (int ks = 0; ks < 4; ++ks)
#pragma unroll
      for (int r = 0; r < 4; ++r)
        Pl[(l4 * 4 + r) * 72 + ks * 16 + l15] = f2b(sacc[ks][r]);
    asm volatile("s_waitcnt lgkmcnt(0)" ::: "memory");
    // PV
#pragma unroll
    for (int kc2 = 0; kc2 < 2; ++kc2) {
      short8 ap = *(const short8*)&Pl[l15 * 72 + kc2 * 32 + l4 * 8];
      const u16* Vp = Vbase + (size_t)l15 * SEQQ + k0 + kc2 * 32 + l4 * 8;
#pragma unroll
      for (int db = 0; db < 8; ++db) {
        short8 bv = *(const short8*)(Vp + (size_t)db * 16 * SEQQ);
        facc[db] = __builtin_amdgcn_mfma_f32_16x16x32_bf16(ap, bv, facc[db], 0, 0, 0);
      }
    }
  }
  u16* Op = O + (size_t)(b * SEQQ + qw) * D_MODEL + h * DK;
  float inv[4];
#pragma unroll
  for (int r = 0; r < 4; ++r) inv[r] = 1.0f / lrun[r];
#pragma unroll
  for (int db = 0; db < 8; ++db)
#pragma unroll
    for (int r = 0; r < 4; ++r)
      Op[(size_t)(l4 * 4 + r) * D_MODEL + db * 16 + l15] = f2b(facc[db][r] * inv[r]);
}

extern "C" void kernel_launch(void* const* d_in, const int* in_sizes, int n_in,
                              void* d_out, int out_size, void* d_ws, size_t ws_size,
                              hipStream_t stream) {
  const float* x   = (const float*)d_in[0];
  const int*   pos = (const int*)d_in[1];
  const float* wq  = (const float*)d_in[2];
  const float* wk  = (const float*)d_in[3];
  const float* wv  = (const float*)d_in[4];
  const float* wo  = (const float*)d_in[5];
  float* out = (float*)d_out;
  char* ws = (char*)d_ws;

  // workspace layout (96 MB, with reuse)
  u16* Xb  = (u16*)(ws);                       // 16 MB, reused as Vt after QKV GEMMs
  u16* Wqb = (u16*)(ws + (16u << 20));
  u16* Wkb = (u16*)(ws + (24u << 20));
  u16* Wvb = (u16*)(ws + (32u << 20));
  u16* Wob = (u16*)(ws + (40u << 20));
  u16* Qb  = (u16*)(ws + (48u << 20));
  u16* Kb  = (u16*)(ws + (64u << 20));
  u16* Vb  = (u16*)(ws + (80u << 20));         // reused as attention output
  u16* Vt  = Xb;
  u16* AO  = Vb;

  const int nX = MTOT * D_MODEL;               // 8388608
  const int nW = D_MODEL * D_MODEL;            // 4194304

  cvt_bf16<<<nX / 1024, 256, 0, stream>>>(x,  Xb,  nX / 4);
  cvt_bf16<<<nW / 1024, 256, 0, stream>>>(wq, Wqb, nW / 4);
  cvt_bf16<<<nW / 1024, 256, 0, stream>>>(wk, Wkb, nW / 4);
  cvt_bf16<<<nW / 1024, 256, 0, stream>>>(wv, Wvb, nW / 4);
  cvt_bf16<<<nW / 1024, 256, 0, stream>>>(wo, Wob, nW / 4);

  dim3 gg(D_MODEL / 128, MTOT / 128);          // (16, 32)
  gemm_bt<0><<<gg, 256, 0, stream>>>(Xb, Wqb, Qb, MTOT, D_MODEL, D_MODEL);
  gemm_bt<0><<<gg, 256, 0, stream>>>(Xb, Wkb, Kb, MTOT, D_MODEL, D_MODEL);
  gemm_bt<0><<<gg, 256, 0, stream>>>(Xb, Wvb, Vb, MTOT, D_MODEL, D_MODEL);

  rope_k<<<(MTOT * 1024) / 256, 256, 0, stream>>>(Qb, pos);
  rope_k<<<(MTOT * 1024) / 256, 256, 0, stream>>>(Kb, pos);

  transpose_v<<<dim3(SEQQ / 32, DK / 32, BATCH * NHEAD), 256, 0, stream>>>(Vb, Vt);

  attn_fwd<<<dim3(SEQQ / 64, BATCH * NHEAD), 256, 0, stream>>>(Qb, Kb, Vt, AO);

  gemm_bt<1><<<gg, 256, 0, stream>>>(AO, Wob, (void*)out, MTOT, D_MODEL, D_MODEL);
}

// Round 2
// 409.043 us; speedup vs baseline: 1.9234x; 1.9234x over previous
//
#include <hip/hip_runtime.h>
#include <cstdint>

typedef unsigned short u16;
typedef __attribute__((ext_vector_type(8))) short short8;
typedef __attribute__((ext_vector_type(4))) float f32x4;

#define D_MODEL 2048
#define NHEAD   16
#define DK      128
#define SEQQ    2048
#define BATCH   2
#define MTOT    (BATCH*SEQQ)   // 4096

__device__ __forceinline__ u16 f2b(float f) {
  union { float f; uint32_t u; } c; c.f = f;
  uint32_t u = c.u;
  u += 0x7fffu + ((u >> 16) & 1u);
  return (u16)(u >> 16);
}
__device__ __forceinline__ float b2f(u16 h) {
  union { uint32_t u; float f; } c; c.u = ((uint32_t)h) << 16;
  return c.f;
}

__device__ __forceinline__ void gload_lds16(const void* g, void* l) {
  __builtin_amdgcn_global_load_lds(
      (const __attribute__((address_space(1))) void*)(uintptr_t)g,
      (__attribute__((address_space(3))) void*)(uint32_t)(uintptr_t)l,
      16, 0, 0);
}

// ---------------- f32 -> bf16 convert (vector 4) ----------------
__global__ __launch_bounds__(256) void cvt_bf16(const float* __restrict__ src,
                                                u16* __restrict__ dst, int n4) {
  int i = blockIdx.x * 256 + threadIdx.x;
  if (i >= n4) return;
  float4 v = ((const float4*)src)[i];
  union { u16 s[4]; uint64_t q; } o;
  o.s[0] = f2b(v.x); o.s[1] = f2b(v.y); o.s[2] = f2b(v.z); o.s[3] = f2b(v.w);
  ((uint64_t*)dst)[i] = o.q;
}

// ---------------- GEMM: C[M,N] = A[M,K] * B[N,K]^T ----------------
template<int F32OUT>
__global__ __launch_bounds__(256) void gemm_bt(const u16* __restrict__ A,
                                               const u16* __restrict__ B,
                                               void* __restrict__ Cout,
                                               int M, int N, int K) {
  __shared__ __align__(16) u16 As[128*32];
  __shared__ __align__(16) u16 Bs[128*32];
  const int tid  = threadIdx.x;
  const int lane = tid & 63;
  const int wave = tid >> 6;
  const int l15 = lane & 15, l4 = lane >> 4;
  const int m0 = blockIdx.y * 128, n0 = blockIdx.x * 128;
  const int wm = (wave >> 1) * 64, wn = (wave & 1) * 64;
  const int srow = tid >> 2;
  const int scol = (tid & 3) * 8;
  const u16* Ag = A + (size_t)(m0 + srow) * K + scol;
  const u16* Bg = B + (size_t)(n0 + srow) * K + scol;
  u16* al = As + (tid >> 6) * 512;
  u16* bl = Bs + (tid >> 6) * 512;

  f32x4 acc[4][4] = {};
  const int nkt = K / 32;
  for (int kt = 0; kt < nkt; ++kt) {
    __syncthreads();
    const u16* a0 = Ag + kt * 32;
    const u16* b0 = Bg + kt * 32;
    gload_lds16(a0,                  al);
    gload_lds16(a0 + (size_t)64 * K, al + 2048);
    gload_lds16(b0,                  bl);
    gload_lds16(b0 + (size_t)64 * K, bl + 2048);
    __syncthreads();
    short8 af[4], bfr[4];
#pragma unroll
    for (int m = 0; m < 4; ++m)
      af[m] = *(const short8*)&As[(wm + m*16 + l15)*32 + l4*8];
#pragma unroll
    for (int n = 0; n < 4; ++n)
      bfr[n] = *(const short8*)&Bs[(wn + n*16 + l15)*32 + l4*8];
#pragma unroll
    for (int m = 0; m < 4; ++m)
#pragma unroll
      for (int n = 0; n < 4; ++n)
        acc[m][n] = __builtin_amdgcn_mfma_f32_16x16x32_bf16(af[m], bfr[n], acc[m][n], 0, 0, 0);
  }
#pragma unroll
  for (int m = 0; m < 4; ++m) {
    const int row = m0 + wm + m*16 + l4*4;
#pragma unroll
    for (int n = 0; n < 4; ++n) {
      const int col = n0 + wn + n*16 + l15;
#pragma unroll
      for (int r = 0; r < 4; ++r) {
        if (F32OUT)
          ((float*)Cout)[(size_t)(row + r) * N + col] = acc[m][n][r];
        else
          ((u16*)Cout)[(size_t)(row + r) * N + col] = f2b(acc[m][n][r]);
      }
    }
  }
}

// ---------------- RoPE in-place on [MTOT][D_MODEL] bf16 ----------------
__global__ __launch_bounds__(256) void rope_k(u16* __restrict__ X, const int* __restrict__ pos) {
  int p = blockIdx.x * 256 + threadIdx.x;
  int m = p >> 10, j2 = p & 1023;
  int h = j2 >> 6, j = j2 & 63;
  int s = m & (SEQQ - 1);
  float fp = (float)pos[s];
  float freq = exp2f((float)j * -0.20762050593046014f);
  float ang = fp * freq;
  float sn, cs;
  sincosf(ang, &sn, &cs);
  u16* px = X + (size_t)m * D_MODEL + h * DK + 2 * j;
  uint32_t pair = *(uint32_t*)px;
  float x1 = b2f((u16)(pair & 0xffff)), x2 = b2f((u16)(pair >> 16));
  u16 r1 = f2b(x1 * cs - x2 * sn);
  u16 r2 = f2b(x1 * sn + x2 * cs);
  *(uint32_t*)px = (uint32_t)r1 | ((uint32_t)r2 << 16);
}

// ---------------- V transpose: [b,s,h,d] -> [bh, d, s] ----------------
__global__ __launch_bounds__(256) void transpose_v(const u16* __restrict__ V, u16* __restrict__ Vt) {
  __shared__ u16 t[32][33];
  const int bh = blockIdx.z;
  const int d0 = blockIdx.y * 32;
  const int s0 = blockIdx.x * 32;
  const int b = bh >> 4, h = bh & 15;
  const int tid = threadIdx.x;
  for (int i = tid; i < 1024; i += 256) {
    int si = i >> 5, di = i & 31;
    t[si][di] = V[(size_t)(b * SEQQ + s0 + si) * D_MODEL + h * DK + d0 + di];
  }
  __syncthreads();
  for (int i = tid; i < 1024; i += 256) {
    int di = i >> 5, si = i & 31;
    Vt[((size_t)bh * DK + d0 + di) * SEQQ + s0 + si] = t[si][di];
  }
}

// ---------------- Flash attention (causal), bf16 MFMA, v2 ----------------
// grid (BATCH*NHEAD=32, 16), 256 threads = 4 waves; wave w handles 32 queries.
// K/V tiles staged in LDS (XOR-swizzled via pre-swizzled global source).
__global__ __launch_bounds__(256) void attn_fwd(const u16* __restrict__ Q,
                                                const u16* __restrict__ Kg,
                                                const u16* __restrict__ Vt,
                                                u16* __restrict__ O) {
  __shared__ __align__(16) u16 Klds[64 * 128];     // [k 64][d 128], swizzled
  __shared__ __align__(16) u16 Vlds[128 * 64];     // [d 128][s 64], swizzled
  __shared__ __align__(16) u16 Plds[4][32 * 72];   // per-wave P, padded stride 72
  const int tid = threadIdx.x, wave = tid >> 6, lane = tid & 63;
  const int l15 = lane & 15, l4 = lane >> 4;
  const int bh = blockIdx.x;
  const int bxr = 15 - (int)blockIdx.y;            // heavy causal blocks dispatch first
  const int b = bh >> 4, h = bh & 15;
  const int q0 = bxr * 128, qw = q0 + wave * 32;
  // 1/sqrt(128) * log2(e): base-2 softmax, fold into Q once
  const float qscale = 0.1275174470974136f;

  // Q fragments, prescaled
  short8 aq[2][4];
#pragma unroll
  for (int qt = 0; qt < 2; ++qt) {
    const u16* Qp = Q + (size_t)(b * SEQQ + qw + qt * 16 + l15) * D_MODEL + h * DK + l4 * 8;
#pragma unroll
    for (int kc = 0; kc < 4; ++kc) {
      short8 raw = *(const short8*)(Qp + kc * 32);
#pragma unroll
      for (int j = 0; j < 8; ++j) raw[j] = (short)f2b(b2f((u16)raw[j]) * qscale);
      aq[qt][kc] = raw;
    }
  }

  f32x4 facc[2][8] = {};
  float mrun[2][4], lrun[2][4];
#pragma unroll
  for (int qt = 0; qt < 2; ++qt)
#pragma unroll
    for (int r = 0; r < 4; ++r) { mrun[qt][r] = -1e30f; lrun[qt][r] = 0.f; }

  const u16* Kbase = Kg + (size_t)b * SEQQ * D_MODEL + h * DK;
  const u16* Vbase = Vt + (size_t)bh * DK * SEQQ;

  // staging source pointers (pre-swizzled global addresses; LDS dest stays linear)
  const u16* ksrc[4]; const u16* vsrc[4];
  u16* kdst[4]; u16* vdst[4];
#pragma unroll
  for (int g = 0; g < 4; ++g) {
    int kr = g * 16 + (tid >> 4);
    int kc = ((tid & 15) * 8) ^ ((kr & 7) << 3);
    ksrc[g] = Kbase + (size_t)kr * D_MODEL + kc;
    kdst[g] = Klds + g * 2048 + wave * 512;
    int vr = g * 32 + (tid >> 3);
    int vc = ((tid & 7) * 8) ^ ((vr & 7) << 3);
    vsrc[g] = Vbase + (size_t)vr * SEQQ + vc;
    vdst[g] = Vlds + g * 2048 + wave * 512;
  }

  u16* Pl = Plds[wave];
  const int nkt = 2 * (bxr + 1);

  for (int kt = 0; kt < nkt; ++kt) {
    const int k0 = kt * 64;
    __syncthreads();                 // previous tile's LDS reads complete
#pragma unroll
    for (int g = 0; g < 4; ++g) {
      gload_lds16(ksrc[g], kdst[g]); ksrc[g] += (size_t)64 * D_MODEL;
      gload_lds16(vsrc[g], vdst[g]); vsrc[g] += 64;
    }
    __syncthreads();                 // vmcnt(0) drained -> LDS tiles visible

    if (k0 <= qw + 31) {
      // ---- QK^T ----
      f32x4 sacc[2][4] = {};
#pragma unroll
      for (int ks = 0; ks < 4; ++ks) {
        const int row = ks * 16 + l15;
        short8 bk[4];
#pragma unroll
        for (int kc = 0; kc < 4; ++kc)
          bk[kc] = *(const short8*)&Klds[row * 128 + ((kc * 32 + l4 * 8) ^ ((row & 7) << 3))];
#pragma unroll
        for (int qt = 0; qt < 2; ++qt)
#pragma unroll
          for (int kc = 0; kc < 4; ++kc)
            sacc[qt][ks] = __builtin_amdgcn_mfma_f32_16x16x32_bf16(aq[qt][kc], bk[kc], sacc[qt][ks], 0, 0, 0);
      }
      // ---- mask + row max ----
      float pmax[2][4];
#pragma unroll
      for (int qt = 0; qt < 2; ++qt) {
        const int qb = qw + qt * 16;
        const bool dg = (k0 + 63 > qb);
#pragma unroll
        for (int r = 0; r < 4; ++r) pmax[qt][r] = -1e30f;
#pragma unroll
        for (int ks = 0; ks < 4; ++ks)
#pragma unroll
          for (int r = 0; r < 4; ++r) {
            float s = sacc[qt][ks][r];
            if (dg && (k0 + ks * 16 + l15 > qb + l4 * 4 + r)) s = -1e30f;
            sacc[qt][ks][r] = s;
            pmax[qt][r] = fmaxf(pmax[qt][r], s);
          }
      }
#pragma unroll
      for (int off = 1; off < 16; off <<= 1)
#pragma unroll
        for (int qt = 0; qt < 2; ++qt)
#pragma unroll
          for (int r = 0; r < 4; ++r)
            pmax[qt][r] = fmaxf(pmax[qt][r], __shfl_xor(pmax[qt][r], off, 64));
      // ---- online softmax ----
      float alpha[2][4], rsum[2][4];
#pragma unroll
      for (int qt = 0; qt < 2; ++qt)
#pragma unroll
        for (int r = 0; r < 4; ++r) {
          float mn = fmaxf(mrun[qt][r], pmax[qt][r]);
          alpha[qt][r] = exp2f(mrun[qt][r] - mn);
          mrun[qt][r] = mn;
          rsum[qt][r] = 0.f;
        }
#pragma unroll
      for (int qt = 0; qt < 2; ++qt)
#pragma unroll
        for (int ks = 0; ks < 4; ++ks)
#pragma unroll
          for (int r = 0; r < 4; ++r) {
            float pv = exp2f(sacc[qt][ks][r] - mrun[qt][r]);
            sacc[qt][ks][r] = pv;
            rsum[qt][r] += pv;
          }
#pragma unroll
      for (int off = 1; off < 16; off <<= 1)
#pragma unroll
        for (int qt = 0; qt < 2; ++qt)
#pragma unroll
          for (int r = 0; r < 4; ++r)
            rsum[qt][r] += __shfl_xor(rsum[qt][r], off, 64);
#pragma unroll
      for (int qt = 0; qt < 2; ++qt)
#pragma unroll
        for (int r = 0; r < 4; ++r)
          lrun[qt][r] = lrun[qt][r] * alpha[qt][r] + rsum[qt][r];
#pragma unroll
      for (int qt = 0; qt < 2; ++qt)
#pragma unroll
        for (int db = 0; db < 8; ++db)
#pragma unroll
          for (int r = 0; r < 4; ++r) facc[qt][db][r] *= alpha[qt][r];
      // ---- P -> LDS (per-wave, bf16) ----
#pragma unroll
      for (int qt = 0; qt < 2; ++qt)
#pragma unroll
        for (int ks = 0; ks < 4; ++ks)
#pragma unroll
          for (int r = 0; r < 4; ++r)
            Pl[(qt * 16 + l4 * 4 + r) * 72 + ks * 16 + l15] = f2b(sacc[qt][ks][r]);
      asm volatile("s_waitcnt lgkmcnt(0)" ::: "memory");
      // ---- PV ----
#pragma unroll
      for (int kc2 = 0; kc2 < 2; ++kc2) {
        short8 ap0 = *(const short8*)&Pl[l15 * 72 + kc2 * 32 + l4 * 8];
        short8 ap1 = *(const short8*)&Pl[(16 + l15) * 72 + kc2 * 32 + l4 * 8];
#pragma unroll
        for (int db = 0; db < 8; ++db) {
          const int row = db * 16 + l15;
          short8 bv = *(const short8*)&Vlds[row * 64 + ((kc2 * 32 + l4 * 8) ^ ((row & 7) << 3))];
          facc[0][db] = __builtin_amdgcn_mfma_f32_16x16x32_bf16(ap0, bv, facc[0][db], 0, 0, 0);
          facc[1][db] = __builtin_amdgcn_mfma_f32_16x16x32_bf16(ap1, bv, facc[1][db], 0, 0, 0);
        }
      }
    }
  }
  // ---- epilogue ----
#pragma unroll
  for (int qt = 0; qt < 2; ++qt) {
    u16* Op = O + (size_t)(b * SEQQ + qw + qt * 16) * D_MODEL + h * DK;
    float inv[4];
#pragma unroll
    for (int r = 0; r < 4; ++r) inv[r] = 1.0f / lrun[qt][r];
#pragma unroll
    for (int db = 0; db < 8; ++db)
#pragma unroll
      for (int r = 0; r < 4; ++r)
        Op[(size_t)(l4 * 4 + r) * D_MODEL + db * 16 + l15] = f2b(facc[qt][db][r] * inv[r]);
  }
}

extern "C" void kernel_launch(void* const* d_in, const int* in_sizes, int n_in,
                              void* d_out, int out_size, void* d_ws, size_t ws_size,
                              hipStream_t stream) {
  const float* x   = (const float*)d_in[0];
  const int*   pos = (const int*)d_in[1];
  const float* wq  = (const float*)d_in[2];
  const float* wk  = (const float*)d_in[3];
  const float* wv  = (const float*)d_in[4];
  const float* wo  = (const float*)d_in[5];
  float* out = (float*)d_out;
  char* ws = (char*)d_ws;

  u16* Xb  = (u16*)(ws);
  u16* Wqb = (u16*)(ws + (16u << 20));
  u16* Wkb = (u16*)(ws + (24u << 20));
  u16* Wvb = (u16*)(ws + (32u << 20));
  u16* Wob = (u16*)(ws + (40u << 20));
  u16* Qb  = (u16*)(ws + (48u << 20));
  u16* Kb  = (u16*)(ws + (64u << 20));
  u16* Vb  = (u16*)(ws + (80u << 20));
  u16* Vt  = Xb;
  u16* AO  = Vb;

  const int nX = MTOT * D_MODEL;
  const int nW = D_MODEL * D_MODEL;

  cvt_bf16<<<nX / 1024, 256, 0, stream>>>(x,  Xb,  nX / 4);
  cvt_bf16<<<nW / 1024, 256, 0, stream>>>(wq, Wqb, nW / 4);
  cvt_bf16<<<nW / 1024, 256, 0, stream>>>(wk, Wkb, nW / 4);
  cvt_bf16<<<nW / 1024, 256, 0, stream>>>(wv, Wvb, nW / 4);
  cvt_bf16<<<nW / 1024, 256, 0, stream>>>(wo, Wob, nW / 4);

  dim3 gg(D_MODEL / 128, MTOT / 128);
  gemm_bt<0><<<gg, 256, 0, stream>>>(Xb, Wqb, Qb, MTOT, D_MODEL, D_MODEL);
  gemm_bt<0><<<gg, 256, 0, stream>>>(Xb, Wkb, Kb, MTOT, D_MODEL, D_MODEL);
  gemm_bt<0><<<gg, 256, 0, stream>>>(Xb, Wvb, Vb, MTOT, D_MODEL, D_MODEL);

  rope_k<<<(MTOT * 1024) / 256, 256, 0, stream>>>(Qb, pos);
  rope_k<<<(MTOT * 1024) / 256, 256, 0, stream>>>(Kb, pos);

  transpose_v<<<dim3(SEQQ / 32, DK / 32, BATCH * NHEAD), 256, 0, stream>>>(Vb, Vt);

  attn_fwd<<<dim3(BATCH * NHEAD, SEQQ / 128), 256, 0, stream>>>(Qb, Kb, Vt, AO);

  gemm_bt<1><<<gg, 256, 0, stream>>>(AO, Wob, (void*)out, MTOT, D_MODEL, D_MODEL);
}

// Round 3
// 338.560 us; speedup vs baseline: 2.3238x; 1.2082x over previous
//
#include <hip/hip_runtime.h>
#include <cstdint>

typedef unsigned short u16;
typedef __attribute__((ext_vector_type(8))) short short8;
typedef __attribute__((ext_vector_type(4))) float f32x4;

#define D_MODEL 2048
#define NHEAD   16
#define DK      128
#define SEQQ    2048
#define BATCH   2
#define MTOT    (BATCH*SEQQ)   // 4096

#define FENCE() asm volatile("" ::: "memory")
#define BARRIER() do { FENCE(); __builtin_amdgcn_s_barrier(); FENCE(); } while (0)

__device__ __forceinline__ u16 f2b(float f) {
  union { float f; uint32_t u; } c; c.f = f;
  uint32_t u = c.u;
  u += 0x7fffu + ((u >> 16) & 1u);
  return (u16)(u >> 16);
}
__device__ __forceinline__ float b2f(u16 h) {
  union { uint32_t u; float f; } c; c.u = ((uint32_t)h) << 16;
  return c.f;
}

__device__ __forceinline__ void gload_lds16(const void* g, void* l) {
  __builtin_amdgcn_global_load_lds(
      (const __attribute__((address_space(1))) void*)(uintptr_t)g,
      (__attribute__((address_space(3))) void*)(uint32_t)(uintptr_t)l,
      16, 0, 0);
}

// ---------------- f32 -> bf16 convert (vector 4) ----------------
__global__ __launch_bounds__(256) void cvt_bf16(const float* __restrict__ src,
                                                u16* __restrict__ dst, int n4) {
  int i = blockIdx.x * 256 + threadIdx.x;
  if (i >= n4) return;
  float4 v = ((const float4*)src)[i];
  union { u16 s[4]; uint64_t q; } o;
  o.s[0] = f2b(v.x); o.s[1] = f2b(v.y); o.s[2] = f2b(v.z); o.s[3] = f2b(v.w);
  ((uint64_t*)dst)[i] = o.q;
}

// ============ 8-phase-style GEMM: C[M,N] = A[M,2048] * B[N,2048]^T ============
// BM=128, BN=256, BK=64. 512 threads = 8 waves (2 x 4), wave output 64x64.
// Ring-3 LDS; counted vmcnt(6) before barrier; XOR swizzle slot^=(row&7);
// raw s_barrier (no compiler vmcnt(0) drain); setprio around MFMA clusters.
// MODE 0: route bf16 output to Cq/Ck/Cv by 2048-col region (QKV fused).
// MODE 1: f32 output to Cf (N=2048).
template<int MODE>
__global__ __launch_bounds__(512) void gemm8(const u16* __restrict__ A,
                                             const u16* __restrict__ B,
                                             u16* __restrict__ Cq, u16* __restrict__ Ck,
                                             u16* __restrict__ Cv, float* __restrict__ Cf,
                                             int cpx) {
  __shared__ __align__(16) u16 As[3][128 * 64];   // 48 KB
  __shared__ __align__(16) u16 Bs[3][256 * 64];   // 96 KB
  const int tid = threadIdx.x;
  const int wave = tid >> 6, lane = tid & 63;
  const int l15 = lane & 15, l4 = lane >> 4;
  const int wr = wave >> 2, wc = wave & 3;
  const int wg = ((int)blockIdx.x & 7) * cpx + ((int)blockIdx.x >> 3);  // XCD swizzle (nblocks%8==0)
  const int bm = wg & 31, bn = wg >> 5;           // M/128 = 32 always
  const int row0 = bm * 128, col0 = bn * 256;

  // staging sources: pre-swizzled global columns (LDS dest stays linear, rule #21)
  const u16* asrc[2]; const u16* bsrc[4];
  {
    const int r = tid >> 3, c8 = tid & 7;
#pragma unroll
    for (int p = 0; p < 2; ++p) {
      int row = p * 64 + r;
      asrc[p] = A + (size_t)(row0 + row) * 2048 + ((c8 ^ (row & 7)) << 3);
    }
#pragma unroll
    for (int p = 0; p < 4; ++p) {
      int row = p * 64 + r;
      bsrc[p] = B + (size_t)(col0 + row) * 2048 + ((c8 ^ (row & 7)) << 3);
    }
  }
  const int ldst = wave * 512 + lane * 8;         // u16 idx; = linear base + lane*16B

  // ds_read fragment offsets (u16 idx), swizzled: slot8 = (ks*4+l4) ^ (l15&7)
  int aoff[4][2], boff[4][2];
#pragma unroll
  for (int m = 0; m < 4; ++m) {
    int row = wr * 64 + m * 16 + l15;
#pragma unroll
    for (int ks = 0; ks < 2; ++ks)
      aoff[m][ks] = row * 64 + (((ks * 4 + l4) ^ (l15 & 7)) << 3);
  }
#pragma unroll
  for (int n = 0; n < 4; ++n) {
    int row = wc * 64 + n * 16 + l15;
#pragma unroll
    for (int ks = 0; ks < 2; ++ks)
      boff[n][ks] = row * 64 + (((ks * 4 + l4) ^ (l15 & 7)) << 3);
  }

  f32x4 acc[4][4] = {};

#define STAGE0(slot, kt) do { \
    gload_lds16(asrc[0] + ((kt) << 6), &As[slot][0 * 4096 + ldst]); \
    gload_lds16(asrc[1] + ((kt) << 6), &As[slot][1 * 4096 + ldst]); \
    gload_lds16(bsrc[0] + ((kt) << 6), &Bs[slot][0 * 4096 + ldst]); \
  } while (0)
#define STAGE1(slot, kt) do { \
    gload_lds16(bsrc[1] + ((kt) << 6), &Bs[slot][1 * 4096 + ldst]); \
    gload_lds16(bsrc[2] + ((kt) << 6), &Bs[slot][2 * 4096 + ldst]); \
    gload_lds16(bsrc[3] + ((kt) << 6), &Bs[slot][3 * 4096 + ldst]); \
  } while (0)

  // prologue: stage tiles 0 and 1 (12 loads), wait so tile0 is landed (6 newest fly)
  STAGE0(0, 0); STAGE1(0, 0);
  STAGE0(1, 1); STAGE1(1, 1);
  asm volatile("s_waitcnt vmcnt(6)" ::: "memory");
  BARRIER();

  int slot = 0;
  for (int t = 0; t < 32; ++t) {
    const int slot2 = slot ? slot - 1 : 2;        // (t+2)%3
    const bool pf = (t + 2 < 32);
    short8 af[4], bf[4];
    // ---- phase 0 (ks=0) ----
#pragma unroll
    for (int m = 0; m < 4; ++m) af[m] = *(const short8*)&As[slot][aoff[m][0]];
#pragma unroll
    for (int n = 0; n < 4; ++n) bf[n] = *(const short8*)&Bs[slot][boff[n][0]];
    if (pf) STAGE0(slot2, t + 2);
    BARRIER();
    __builtin_amdgcn_s_setprio(1);
#pragma unroll
    for (int m = 0; m < 4; ++m)
#pragma unroll
      for (int n = 0; n < 4; ++n)
        acc[m][n] = __builtin_amdgcn_mfma_f32_16x16x32_bf16(af[m], bf[n], acc[m][n], 0, 0, 0);
    __builtin_amdgcn_s_setprio(0);
    BARRIER();
    // ---- phase 1 (ks=1) ----
#pragma unroll
    for (int m = 0; m < 4; ++m) af[m] = *(const short8*)&As[slot][aoff[m][1]];
#pragma unroll
    for (int n = 0; n < 4; ++n) bf[n] = *(const short8*)&Bs[slot][boff[n][1]];
    if (pf) STAGE1(slot2, t + 2);
    BARRIER();
    __builtin_amdgcn_s_setprio(1);
#pragma unroll
    for (int m = 0; m < 4; ++m)
#pragma unroll
      for (int n = 0; n < 4; ++n)
        acc[m][n] = __builtin_amdgcn_mfma_f32_16x16x32_bf16(af[m], bf[n], acc[m][n], 0, 0, 0);
    __builtin_amdgcn_s_setprio(0);
    // counted wait BEFORE barrier: after barrier, every wave's tile t+1 loads have landed
    if (pf) asm volatile("s_waitcnt vmcnt(6)" ::: "memory");
    else    asm volatile("s_waitcnt vmcnt(0)" ::: "memory");
    BARRIER();
    slot = (slot == 2) ? 0 : slot + 1;
  }
#undef STAGE0
#undef STAGE1

  // epilogue
#pragma unroll
  for (int m = 0; m < 4; ++m) {
    const int row = row0 + wr * 64 + m * 16 + l4 * 4;
#pragma unroll
    for (int n = 0; n < 4; ++n) {
      const int col = wc * 64 + n * 16 + l15;
      if (MODE == 1) {
#pragma unroll
        for (int r = 0; r < 4; ++r)
          Cf[(size_t)(row + r) * 2048 + col0 + col] = acc[m][n][r];
      } else {
        const int region = col0 >> 11;
        u16* Cx = (region == 0) ? Cq : (region == 1) ? Ck : Cv;
        const int col2 = (col0 & 2047) + col;
#pragma unroll
        for (int r = 0; r < 4; ++r)
          Cx[(size_t)(row + r) * 2048 + col2] = f2b(acc[m][n][r]);
      }
    }
  }
}

// ---------------- RoPE in-place on [MTOT][D_MODEL] bf16 ----------------
__global__ __launch_bounds__(256) void rope_k(u16* __restrict__ X, const int* __restrict__ pos) {
  int p = blockIdx.x * 256 + threadIdx.x;
  int m = p >> 10, j2 = p & 1023;
  int h = j2 >> 6, j = j2 & 63;
  int s = m & (SEQQ - 1);
  float fp = (float)pos[s];
  float freq = exp2f((float)j * -0.20762050593046014f);
  float ang = fp * freq;
  float sn, cs;
  sincosf(ang, &sn, &cs);
  u16* px = X + (size_t)m * D_MODEL + h * DK + 2 * j;
  uint32_t pair = *(uint32_t*)px;
  float x1 = b2f((u16)(pair & 0xffff)), x2 = b2f((u16)(pair >> 16));
  u16 r1 = f2b(x1 * cs - x2 * sn);
  u16 r2 = f2b(x1 * sn + x2 * cs);
  *(uint32_t*)px = (uint32_t)r1 | ((uint32_t)r2 << 16);
}

// ---------------- V transpose: [b,s,h,d] -> [bh, d, s] ----------------
__global__ __launch_bounds__(256) void transpose_v(const u16* __restrict__ V, u16* __restrict__ Vt) {
  __shared__ u16 t[32][33];
  const int bh = blockIdx.z;
  const int d0 = blockIdx.y * 32;
  const int s0 = blockIdx.x * 32;
  const int b = bh >> 4, h = bh & 15;
  const int tid = threadIdx.x;
  for (int i = tid; i < 1024; i += 256) {
    int si = i >> 5, di = i & 31;
    t[si][di] = V[(size_t)(b * SEQQ + s0 + si) * D_MODEL + h * DK + d0 + di];
  }
  __syncthreads();
  for (int i = tid; i < 1024; i += 256) {
    int di = i >> 5, si = i & 31;
    Vt[((size_t)bh * DK + d0 + di) * SEQQ + s0 + si] = t[si][di];
  }
}

// ---------------- Flash attention (causal), bf16 MFMA ----------------
__global__ __launch_bounds__(256) void attn_fwd(const u16* __restrict__ Q,
                                                const u16* __restrict__ Kg,
                                                const u16* __restrict__ Vt,
                                                u16* __restrict__ O) {
  __shared__ __align__(16) u16 Klds[64 * 128];
  __shared__ __align__(16) u16 Vlds[128 * 64];
  __shared__ __align__(16) u16 Plds[4][32 * 72];
  const int tid = threadIdx.x, wave = tid >> 6, lane = tid & 63;
  const int l15 = lane & 15, l4 = lane >> 4;
  const int bh = blockIdx.x;
  const int bxr = 15 - (int)blockIdx.y;
  const int b = bh >> 4, h = bh & 15;
  const int q0 = bxr * 128, qw = q0 + wave * 32;
  const float qscale = 0.1275174470974136f;      // 1/sqrt(128)*log2(e)

  short8 aq[2][4];
#pragma unroll
  for (int qt = 0; qt < 2; ++qt) {
    const u16* Qp = Q + (size_t)(b * SEQQ + qw + qt * 16 + l15) * D_MODEL + h * DK + l4 * 8;
#pragma unroll
    for (int kc = 0; kc < 4; ++kc) {
      short8 raw = *(const short8*)(Qp + kc * 32);
#pragma unroll
      for (int j = 0; j < 8; ++j) raw[j] = (short)f2b(b2f((u16)raw[j]) * qscale);
      aq[qt][kc] = raw;
    }
  }

  f32x4 facc[2][8] = {};
  float mrun[2][4], lrun[2][4];
#pragma unroll
  for (int qt = 0; qt < 2; ++qt)
#pragma unroll
    for (int r = 0; r < 4; ++r) { mrun[qt][r] = -1e30f; lrun[qt][r] = 0.f; }

  const u16* Kbase = Kg + (size_t)b * SEQQ * D_MODEL + h * DK;
  const u16* Vbase = Vt + (size_t)bh * DK * SEQQ;

  const u16* ksrc[4]; const u16* vsrc[4];
  u16* kdst[4]; u16* vdst[4];
#pragma unroll
  for (int g = 0; g < 4; ++g) {
    int kr = g * 16 + (tid >> 4);
    int kc = ((tid & 15) * 8) ^ ((kr & 7) << 3);
    ksrc[g] = Kbase + (size_t)kr * D_MODEL + kc;
    kdst[g] = Klds + g * 2048 + wave * 512;
    int vr = g * 32 + (tid >> 3);
    int vc = ((tid & 7) * 8) ^ ((vr & 7) << 3);
    vsrc[g] = Vbase + (size_t)vr * SEQQ + vc;
    vdst[g] = Vlds + g * 2048 + wave * 512;
  }

  u16* Pl = Plds[wave];
  const int nkt = 2 * (bxr + 1);

  for (int kt = 0; kt < nkt; ++kt) {
    const int k0 = kt * 64;
    __syncthreads();
#pragma unroll
    for (int g = 0; g < 4; ++g) {
      gload_lds16(ksrc[g], kdst[g]); ksrc[g] += (size_t)64 * D_MODEL;
      gload_lds16(vsrc[g], vdst[g]); vsrc[g] += 64;
    }
    __syncthreads();

    if (k0 <= qw + 31) {
      f32x4 sacc[2][4] = {};
#pragma unroll
      for (int ks = 0; ks < 4; ++ks) {
        const int row = ks * 16 + l15;
        short8 bk[4];
#pragma unroll
        for (int kc = 0; kc < 4; ++kc)
          bk[kc] = *(const short8*)&Klds[row * 128 + ((kc * 32 + l4 * 8) ^ ((row & 7) << 3))];
#pragma unroll
        for (int qt = 0; qt < 2; ++qt)
#pragma unroll
          for (int kc = 0; kc < 4; ++kc)
            sacc[qt][ks] = __builtin_amdgcn_mfma_f32_16x16x32_bf16(aq[qt][kc], bk[kc], sacc[qt][ks], 0, 0, 0);
      }
      float pmax[2][4];
#pragma unroll
      for (int qt = 0; qt < 2; ++qt) {
        const int qb = qw + qt * 16;
        const bool dg = (k0 + 63 > qb);
#pragma unroll
        for (int r = 0; r < 4; ++r) pmax[qt][r] = -1e30f;
#pragma unroll
        for (int ks = 0; ks < 4; ++ks)
#pragma unroll
          for (int r = 0; r < 4; ++r) {
            float s = sacc[qt][ks][r];
            if (dg && (k0 + ks * 16 + l15 > qb + l4 * 4 + r)) s = -1e30f;
            sacc[qt][ks][r] = s;
            pmax[qt][r] = fmaxf(pmax[qt][r], s);
          }
      }
#pragma unroll
      for (int off = 1; off < 16; off <<= 1)
#pragma unroll
        for (int qt = 0; qt < 2; ++qt)
#pragma unroll
          for (int r = 0; r < 4; ++r)
            pmax[qt][r] = fmaxf(pmax[qt][r], __shfl_xor(pmax[qt][r], off, 64));
      // exact defer-max (THR=0): skip rescale when running max didn't grow
      float alpha[2][4];
      bool res[2];
#pragma unroll
      for (int qt = 0; qt < 2; ++qt) {
        float d = -1e30f;
#pragma unroll
        for (int r = 0; r < 4; ++r) d = fmaxf(d, pmax[qt][r] - mrun[qt][r]);
        res[qt] = !__all(d <= 0.f);
        if (res[qt]) {
#pragma unroll
          for (int r = 0; r < 4; ++r) {
            float mn = fmaxf(mrun[qt][r], pmax[qt][r]);
            alpha[qt][r] = exp2f(mrun[qt][r] - mn);
            mrun[qt][r] = mn;
          }
        }
      }
      float rsum[2][4];
#pragma unroll
      for (int qt = 0; qt < 2; ++qt)
#pragma unroll
        for (int r = 0; r < 4; ++r) rsum[qt][r] = 0.f;
#pragma unroll
      for (int qt = 0; qt < 2; ++qt)
#pragma unroll
        for (int ks = 0; ks < 4; ++ks)
#pragma unroll
          for (int r = 0; r < 4; ++r) {
            float pv = exp2f(sacc[qt][ks][r] - mrun[qt][r]);
            sacc[qt][ks][r] = pv;
            rsum[qt][r] += pv;
          }
#pragma unroll
      for (int off = 1; off < 16; off <<= 1)
#pragma unroll
        for (int qt = 0; qt < 2; ++qt)
#pragma unroll
          for (int r = 0; r < 4; ++r)
            rsum[qt][r] += __shfl_xor(rsum[qt][r], off, 64);
#pragma unroll
      for (int qt = 0; qt < 2; ++qt) {
        if (res[qt]) {
#pragma unroll
          for (int r = 0; r < 4; ++r)
            lrun[qt][r] = lrun[qt][r] * alpha[qt][r] + rsum[qt][r];
#pragma unroll
          for (int db = 0; db < 8; ++db)
#pragma unroll
            for (int r = 0; r < 4; ++r) facc[qt][db][r] *= alpha[qt][r];
        } else {
#pragma unroll
          for (int r = 0; r < 4; ++r) lrun[qt][r] += rsum[qt][r];
        }
      }
#pragma unroll
      for (int qt = 0; qt < 2; ++qt)
#pragma unroll
        for (int ks = 0; ks < 4; ++ks)
#pragma unroll
          for (int r = 0; r < 4; ++r)
            Pl[(qt * 16 + l4 * 4 + r) * 72 + ks * 16 + l15] = f2b(sacc[qt][ks][r]);
      asm volatile("s_waitcnt lgkmcnt(0)" ::: "memory");
#pragma unroll
      for (int kc2 = 0; kc2 < 2; ++kc2) {
        short8 ap0 = *(const short8*)&Pl[l15 * 72 + kc2 * 32 + l4 * 8];
        short8 ap1 = *(const short8*)&Pl[(16 + l15) * 72 + kc2 * 32 + l4 * 8];
#pragma unroll
        for (int db = 0; db < 8; ++db) {
          const int row = db * 16 + l15;
          short8 bv = *(const short8*)&Vlds[row * 64 + ((kc2 * 32 + l4 * 8) ^ ((row & 7) << 3))];
          facc[0][db] = __builtin_amdgcn_mfma_f32_16x16x32_bf16(ap0, bv, facc[0][db], 0, 0, 0);
          facc[1][db] = __builtin_amdgcn_mfma_f32_16x16x32_bf16(ap1, bv, facc[1][db], 0, 0, 0);
        }
      }
    }
  }
#pragma unroll
  for (int qt = 0; qt < 2; ++qt) {
    u16* Op = O + (size_t)(b * SEQQ + qw + qt * 16) * D_MODEL + h * DK;
    float inv[4];
#pragma unroll
    for (int r = 0; r < 4; ++r) inv[r] = 1.0f / lrun[qt][r];
#pragma unroll
    for (int db = 0; db < 8; ++db)
#pragma unroll
      for (int r = 0; r < 4; ++r)
        Op[(size_t)(l4 * 4 + r) * D_MODEL + db * 16 + l15] = f2b(facc[qt][db][r] * inv[r]);
  }
}

extern "C" void kernel_launch(void* const* d_in, const int* in_sizes, int n_in,
                              void* d_out, int out_size, void* d_ws, size_t ws_size,
                              hipStream_t stream) {
  const float* x   = (const float*)d_in[0];
  const int*   pos = (const int*)d_in[1];
  const float* wq  = (const float*)d_in[2];
  const float* wk  = (const float*)d_in[3];
  const float* wv  = (const float*)d_in[4];
  const float* wo  = (const float*)d_in[5];
  float* out = (float*)d_out;
  char* ws = (char*)d_ws;

  u16* Xb   = (u16*)(ws);                      // 16 MB, reused as Vt
  u16* Wqkv = (u16*)(ws + (16u << 20));        // 24 MB (stacked Wq|Wk|Wv rows)
  u16* Wob  = (u16*)(ws + (40u << 20));        // 8 MB
  u16* Qb   = (u16*)(ws + (48u << 20));
  u16* Kb   = (u16*)(ws + (64u << 20));
  u16* Vb   = (u16*)(ws + (80u << 20));        // reused as attention output
  u16* Vt   = Xb;
  u16* AO   = Vb;

  const int nX = MTOT * D_MODEL;
  const int nW = D_MODEL * D_MODEL;

  cvt_bf16<<<nX / 1024, 256, 0, stream>>>(x,  Xb,  nX / 4);
  cvt_bf16<<<nW / 1024, 256, 0, stream>>>(wq, Wqkv,          nW / 4);
  cvt_bf16<<<nW / 1024, 256, 0, stream>>>(wk, Wqkv + nW,     nW / 4);
  cvt_bf16<<<nW / 1024, 256, 0, stream>>>(wv, Wqkv + 2 * nW, nW / 4);
  cvt_bf16<<<nW / 1024, 256, 0, stream>>>(wo, Wob, nW / 4);

  // fused QKV GEMM: M=4096, N=6144, K=2048 -> 24*32 = 768 blocks
  gemm8<0><<<768, 512, 0, stream>>>(Xb, Wqkv, Qb, Kb, Vb, nullptr, 96);

  rope_k<<<(MTOT * 1024) / 256, 256, 0, stream>>>(Qb, pos);
  rope_k<<<(MTOT * 1024) / 256, 256, 0, stream>>>(Kb, pos);

  transpose_v<<<dim3(SEQQ / 32, DK / 32, BATCH * NHEAD), 256, 0, stream>>>(Vb, Vt);

  attn_fwd<<<dim3(BATCH * NHEAD, SEQQ / 128), 256, 0, stream>>>(Qb, Kb, Vt, AO);

  // final GEMM: M=4096, N=2048 -> 8*32 = 256 blocks, f32 out
  gemm8<1><<<256, 512, 0, stream>>>(AO, Wob, nullptr, nullptr, nullptr, out, 32);
}

// Round 4
// 333.222 us; speedup vs baseline: 2.3610x; 1.0160x over previous
//
#include <hip/hip_runtime.h>
#include <cstdint>

typedef unsigned short u16;
typedef __attribute__((ext_vector_type(8))) short short8;
typedef __attribute__((ext_vector_type(4))) float f32x4;

#define D_MODEL 2048
#define NHEAD   16
#define DK      128
#define SEQQ    2048
#define BATCH   2
#define MTOT    (BATCH*SEQQ)   // 4096

#define FENCE() asm volatile("" ::: "memory")
#define BARRIER() do { FENCE(); __builtin_amdgcn_s_barrier(); FENCE(); } while (0)

__device__ __forceinline__ u16 f2b(float f) {
  union { float f; uint32_t u; } c; c.f = f;
  uint32_t u = c.u;
  u += 0x7fffu + ((u >> 16) & 1u);
  return (u16)(u >> 16);
}
__device__ __forceinline__ float b2f(u16 h) {
  union { uint32_t u; float f; } c; c.u = ((uint32_t)h) << 16;
  return c.f;
}

__device__ __forceinline__ void gload_lds16(const void* g, void* l) {
  __builtin_amdgcn_global_load_lds(
      (const __attribute__((address_space(1))) void*)(uintptr_t)g,
      (__attribute__((address_space(3))) void*)(uint32_t)(uintptr_t)l,
      16, 0, 0);
}

// ---------------- f32 -> bf16 convert: X ----------------
__global__ __launch_bounds__(256) void cvt_bf16(const float* __restrict__ src,
                                                u16* __restrict__ dst, int n4) {
  int i = blockIdx.x * 256 + threadIdx.x;
  if (i >= n4) return;
  float4 v = ((const float4*)src)[i];
  union { u16 s[4]; uint64_t q; } o;
  o.s[0] = f2b(v.x); o.s[1] = f2b(v.y); o.s[2] = f2b(v.z); o.s[3] = f2b(v.w);
  ((uint64_t*)dst)[i] = o.q;
}

// ---------------- fused weight converts (wq|wk|wv -> Wqkv, wo -> Wob) ----------------
__global__ __launch_bounds__(256) void cvt_w(const float* __restrict__ wq,
                                             const float* __restrict__ wk,
                                             const float* __restrict__ wv,
                                             const float* __restrict__ wo,
                                             u16* __restrict__ Wqkv,
                                             u16* __restrict__ Wob) {
  int i = blockIdx.x * 256 + threadIdx.x;        // 0 .. 4*2^20
  int which = i >> 20, j = i & 1048575;          // nW/4 = 2^20
  const float* src = (which == 0) ? wq : (which == 1) ? wk : (which == 2) ? wv : wo;
  u16* dst = (which < 3) ? (Wqkv + (size_t)which * 4194304) : Wob;
  float4 v = ((const float4*)src)[j];
  union { u16 s[4]; uint64_t q; } o;
  o.s[0] = f2b(v.x); o.s[1] = f2b(v.y); o.s[2] = f2b(v.z); o.s[3] = f2b(v.w);
  ((uint64_t*)dst)[j] = o.q;
}

// ============ 8-phase-style GEMM: C[M,N] = A[M,2048] * B[N,2048]^T ============
// BM=128, BN=256, BK=64. 512 threads = 8 waves (2 x 4), wave output 64x64.
// Ring-3 LDS; counted vmcnt(6); XOR swizzle; raw s_barrier; setprio on MFMA.
// MODE 0: Q/K regions -> bf16 row-major; V region -> transposed Vt[bh][d][s].
// MODE 1: f32 output to Cf (N=2048).
template<int MODE>
__global__ __launch_bounds__(512) void gemm8(const u16* __restrict__ A,
                                             const u16* __restrict__ B,
                                             u16* __restrict__ Cq, u16* __restrict__ Ck,
                                             u16* __restrict__ Vt, float* __restrict__ Cf,
                                             int cpx) {
  __shared__ __align__(16) u16 As[3][128 * 64];   // 48 KB
  __shared__ __align__(16) u16 Bs[3][256 * 64];   // 96 KB
  const int tid = threadIdx.x;
  const int wave = tid >> 6, lane = tid & 63;
  const int l15 = lane & 15, l4 = lane >> 4;
  const int wr = wave >> 2, wc = wave & 3;
  const int wg = ((int)blockIdx.x & 7) * cpx + ((int)blockIdx.x >> 3);  // XCD swizzle
  const int bm = wg & 31, bn = wg >> 5;
  const int row0 = bm * 128, col0 = bn * 256;

  const u16* asrc[2]; const u16* bsrc[4];
  {
    const int r = tid >> 3, c8 = tid & 7;
#pragma unroll
    for (int p = 0; p < 2; ++p) {
      int row = p * 64 + r;
      asrc[p] = A + (size_t)(row0 + row) * 2048 + ((c8 ^ (row & 7)) << 3);
    }
#pragma unroll
    for (int p = 0; p < 4; ++p) {
      int row = p * 64 + r;
      bsrc[p] = B + (size_t)(col0 + row) * 2048 + ((c8 ^ (row & 7)) << 3);
    }
  }
  const int ldst = wave * 512 + lane * 8;

  int aoff[4][2], boff[4][2];
#pragma unroll
  for (int m = 0; m < 4; ++m) {
    int row = wr * 64 + m * 16 + l15;
#pragma unroll
    for (int ks = 0; ks < 2; ++ks)
      aoff[m][ks] = row * 64 + (((ks * 4 + l4) ^ (l15 & 7)) << 3);
  }
#pragma unroll
  for (int n = 0; n < 4; ++n) {
    int row = wc * 64 + n * 16 + l15;
#pragma unroll
    for (int ks = 0; ks < 2; ++ks)
      boff[n][ks] = row * 64 + (((ks * 4 + l4) ^ (l15 & 7)) << 3);
  }

  f32x4 acc[4][4] = {};

#define STAGE0(slot, kt) do { \
    gload_lds16(asrc[0] + ((kt) << 6), &As[slot][0 * 4096 + ldst]); \
    gload_lds16(asrc[1] + ((kt) << 6), &As[slot][1 * 4096 + ldst]); \
    gload_lds16(bsrc[0] + ((kt) << 6), &Bs[slot][0 * 4096 + ldst]); \
  } while (0)
#define STAGE1(slot, kt) do { \
    gload_lds16(bsrc[1] + ((kt) << 6), &Bs[slot][1 * 4096 + ldst]); \
    gload_lds16(bsrc[2] + ((kt) << 6), &Bs[slot][2 * 4096 + ldst]); \
    gload_lds16(bsrc[3] + ((kt) << 6), &Bs[slot][3 * 4096 + ldst]); \
  } while (0)

  STAGE0(0, 0); STAGE1(0, 0);
  STAGE0(1, 1); STAGE1(1, 1);
  asm volatile("s_waitcnt vmcnt(6)" ::: "memory");
  BARRIER();

  int slot = 0;
  for (int t = 0; t < 32; ++t) {
    const int slot2 = slot ? slot - 1 : 2;
    const bool pf = (t + 2 < 32);
    short8 af[4], bf[4];
#pragma unroll
    for (int m = 0; m < 4; ++m) af[m] = *(const short8*)&As[slot][aoff[m][0]];
#pragma unroll
    for (int n = 0; n < 4; ++n) bf[n] = *(const short8*)&Bs[slot][boff[n][0]];
    if (pf) STAGE0(slot2, t + 2);
    BARRIER();
    __builtin_amdgcn_s_setprio(1);
#pragma unroll
    for (int m = 0; m < 4; ++m)
#pragma unroll
      for (int n = 0; n < 4; ++n)
        acc[m][n] = __builtin_amdgcn_mfma_f32_16x16x32_bf16(af[m], bf[n], acc[m][n], 0, 0, 0);
    __builtin_amdgcn_s_setprio(0);
    BARRIER();
#pragma unroll
    for (int m = 0; m < 4; ++m) af[m] = *(const short8*)&As[slot][aoff[m][1]];
#pragma unroll
    for (int n = 0; n < 4; ++n) bf[n] = *(const short8*)&Bs[slot][boff[n][1]];
    if (pf) STAGE1(slot2, t + 2);
    BARRIER();
    __builtin_amdgcn_s_setprio(1);
#pragma unroll
    for (int m = 0; m < 4; ++m)
#pragma unroll
      for (int n = 0; n < 4; ++n)
        acc[m][n] = __builtin_amdgcn_mfma_f32_16x16x32_bf16(af[m], bf[n], acc[m][n], 0, 0, 0);
    __builtin_amdgcn_s_setprio(0);
    if (pf) asm volatile("s_waitcnt vmcnt(6)" ::: "memory");
    else    asm volatile("s_waitcnt vmcnt(0)" ::: "memory");
    BARRIER();
    slot = (slot == 2) ? 0 : slot + 1;
  }
#undef STAGE0
#undef STAGE1

#pragma unroll
  for (int m = 0; m < 4; ++m) {
    const int row = row0 + wr * 64 + m * 16 + l4 * 4;
#pragma unroll
    for (int n = 0; n < 4; ++n) {
      const int col = wc * 64 + n * 16 + l15;
      if (MODE == 1) {
#pragma unroll
        for (int r = 0; r < 4; ++r)
          Cf[(size_t)(row + r) * 2048 + col0 + col] = acc[m][n][r];
      } else {
        const int region = col0 >> 11;
        const int col2 = (col0 & 2047) + col;
        if (region < 2) {
          u16* Cx = region ? Ck : Cq;
#pragma unroll
          for (int r = 0; r < 4; ++r)
            Cx[(size_t)(row + r) * 2048 + col2] = f2b(acc[m][n][r]);
        } else {
          // V region: write transposed Vt[bh][d][s]; 4 consecutive tokens pack to 8B
          union { u16 h4[4]; uint64_t q; } pk;
#pragma unroll
          for (int r = 0; r < 4; ++r) pk.h4[r] = f2b(acc[m][n][r]);
          const int bb = row >> 11, ss = row & 2047;
          const int hh = col2 >> 7, dd = col2 & 127;
          *(uint64_t*)&Vt[((size_t)((bb << 4) + hh) * 128 + dd) * 2048 + ss] = pk.q;
        }
      }
    }
  }
}

// ---------------- RoPE in-place, fused Q+K ----------------
__global__ __launch_bounds__(256) void rope_qk(u16* __restrict__ Qb, u16* __restrict__ Kb,
                                               const int* __restrict__ pos) {
  int p = blockIdx.x * 256 + threadIdx.x;       // 0 .. 2*2^22
  u16* X = (p >> 22) ? Kb : Qb;
  int pp = p & 4194303;                          // MTOT*1024 = 2^22
  int m = pp >> 10, j2 = pp & 1023;
  int h = j2 >> 6, j = j2 & 63;
  int s = m & (SEQQ - 1);
  float fp = (float)pos[s];
  float freq = exp2f((float)j * -0.20762050593046014f);
  float ang = fp * freq;
  float sn, cs;
  sincosf(ang, &sn, &cs);
  u16* px = X + (size_t)m * D_MODEL + h * DK + 2 * j;
  uint32_t pair = *(uint32_t*)px;
  float x1 = b2f((u16)(pair & 0xffff)), x2 = b2f((u16)(pair >> 16));
  u16 r1 = f2b(x1 * cs - x2 * sn);
  u16 r2 = f2b(x1 * sn + x2 * cs);
  *(uint32_t*)px = (uint32_t)r1 | ((uint32_t)r2 << 16);
}

// ---------------- Flash attention (causal), pipelined staging ----------------
// grid (32, 16), 256 thr = 4 waves, wave w: 32 queries. K double-buffered,
// V staged one iteration early; counted vmcnt per queue {K(t), V(t), K(t+1)}.
__global__ __launch_bounds__(256) void attn_fwd(const u16* __restrict__ Q,
                                                const u16* __restrict__ Kg,
                                                const u16* __restrict__ Vt,
                                                u16* __restrict__ O) {
  __shared__ __align__(16) u16 Klds[2][64 * 128];
  __shared__ __align__(16) u16 Vlds[128 * 64];
  __shared__ __align__(16) u16 Plds[4][32 * 72];
  const int tid = threadIdx.x, wave = tid >> 6, lane = tid & 63;
  const int l15 = lane & 15, l4 = lane >> 4;
  const int bh = blockIdx.x;
  const int bxr = 15 - (int)blockIdx.y;
  const int b = bh >> 4, h = bh & 15;
  const int q0 = bxr * 128, qw = q0 + wave * 32;
  const float qscale = 0.1275174470974136f;      // 1/sqrt(128)*log2(e)

  short8 aq[2][4];
#pragma unroll
  for (int qt = 0; qt < 2; ++qt) {
    const u16* Qp = Q + (size_t)(b * SEQQ + qw + qt * 16 + l15) * D_MODEL + h * DK + l4 * 8;
#pragma unroll
    for (int kc = 0; kc < 4; ++kc) {
      short8 raw = *(const short8*)(Qp + kc * 32);
#pragma unroll
      for (int j = 0; j < 8; ++j) raw[j] = (short)f2b(b2f((u16)raw[j]) * qscale);
      aq[qt][kc] = raw;
    }
  }
  asm volatile("s_waitcnt vmcnt(0)" ::: "memory");   // Q-loads drained: counted waits exact

  f32x4 facc[2][8] = {};
  float mrun[2][4], lrun[2][4];
#pragma unroll
  for (int qt = 0; qt < 2; ++qt)
#pragma unroll
    for (int r = 0; r < 4; ++r) { mrun[qt][r] = -1e30f; lrun[qt][r] = 0.f; }

  const u16* Kbase = Kg + (size_t)b * SEQQ * D_MODEL + h * DK;
  const u16* Vbase = Vt + (size_t)bh * DK * SEQQ;

  const u16* ksrc[4]; const u16* vsrc[4];
#pragma unroll
  for (int g = 0; g < 4; ++g) {
    int kr = g * 16 + (tid >> 4);
    int kc = ((tid & 15) * 8) ^ ((kr & 7) << 3);
    ksrc[g] = Kbase + (size_t)kr * D_MODEL + kc;
    int vr = g * 32 + (tid >> 3);
    int vc = ((tid & 7) * 8) ^ ((vr & 7) << 3);
    vsrc[g] = Vbase + (size_t)vr * SEQQ + vc;
  }
  const int dstoff = tid * 8;

  const int nkt = 2 * (bxr + 1);
  // prologue: K(0), V(0)
#pragma unroll
  for (int g = 0; g < 4; ++g) { gload_lds16(ksrc[g], &Klds[0][g * 2048 + dstoff]); ksrc[g] += (size_t)64 * D_MODEL; }
#pragma unroll
  for (int g = 0; g < 4; ++g) { gload_lds16(vsrc[g], &Vlds[g * 2048 + dstoff]); vsrc[g] += 64; }

  u16* Pl = Plds[wave];

  for (int kt = 0; kt < nkt; ++kt) {
    const int k0 = kt * 64;
    const int cur = kt & 1;
    const bool morek = (kt + 1 < nkt);
    if (morek) {
#pragma unroll
      for (int g = 0; g < 4; ++g) { gload_lds16(ksrc[g], &Klds[cur ^ 1][g * 2048 + dstoff]); ksrc[g] += (size_t)64 * D_MODEL; }
      asm volatile("s_waitcnt vmcnt(8)" ::: "memory");   // K(t) landed; V(t)+K(t+1) fly
    } else {
      asm volatile("s_waitcnt vmcnt(4)" ::: "memory");   // K(t) landed; V(t) flies
    }
    BARRIER();

    const bool active = (k0 <= qw + 31);
    if (active) {
      f32x4 sacc[2][4] = {};
      __builtin_amdgcn_s_setprio(1);
#pragma unroll
      for (int ks = 0; ks < 4; ++ks) {
        const int row = ks * 16 + l15;
        short8 bk[4];
#pragma unroll
        for (int kc = 0; kc < 4; ++kc)
          bk[kc] = *(const short8*)&Klds[cur][row * 128 + ((kc * 32 + l4 * 8) ^ ((row & 7) << 3))];
#pragma unroll
        for (int qt = 0; qt < 2; ++qt)
#pragma unroll
          for (int kc = 0; kc < 4; ++kc)
            sacc[qt][ks] = __builtin_amdgcn_mfma_f32_16x16x32_bf16(aq[qt][kc], bk[kc], sacc[qt][ks], 0, 0, 0);
      }
      __builtin_amdgcn_s_setprio(0);
      float pmax[2][4];
#pragma unroll
      for (int qt = 0; qt < 2; ++qt) {
        const int qb = qw + qt * 16;
        const bool dg = (k0 + 63 > qb);
#pragma unroll
        for (int r = 0; r < 4; ++r) pmax[qt][r] = -1e30f;
#pragma unroll
        for (int ks = 0; ks < 4; ++ks)
#pragma unroll
          for (int r = 0; r < 4; ++r) {
            float s = sacc[qt][ks][r];
            if (dg && (k0 + ks * 16 + l15 > qb + l4 * 4 + r)) s = -1e30f;
            sacc[qt][ks][r] = s;
            pmax[qt][r] = fmaxf(pmax[qt][r], s);
          }
      }
#pragma unroll
      for (int off = 1; off < 16; off <<= 1)
#pragma unroll
        for (int qt = 0; qt < 2; ++qt)
#pragma unroll
          for (int r = 0; r < 4; ++r)
            pmax[qt][r] = fmaxf(pmax[qt][r], __shfl_xor(pmax[qt][r], off, 64));
      float alpha[2][4], rsum[2][4];
#pragma unroll
      for (int qt = 0; qt < 2; ++qt)
#pragma unroll
        for (int r = 0; r < 4; ++r) {
          float mn = fmaxf(mrun[qt][r], pmax[qt][r]);
          alpha[qt][r] = exp2f(mrun[qt][r] - mn);
          mrun[qt][r] = mn;
          rsum[qt][r] = 0.f;
        }
#pragma unroll
      for (int qt = 0; qt < 2; ++qt)
#pragma unroll
        for (int ks = 0; ks < 4; ++ks)
#pragma unroll
          for (int r = 0; r < 4; ++r) {
            float pv = exp2f(sacc[qt][ks][r] - mrun[qt][r]);
            sacc[qt][ks][r] = pv;
            rsum[qt][r] += pv;
          }
#pragma unroll
      for (int off = 1; off < 16; off <<= 1)
#pragma unroll
        for (int qt = 0; qt < 2; ++qt)
#pragma unroll
          for (int r = 0; r < 4; ++r)
            rsum[qt][r] += __shfl_xor(rsum[qt][r], off, 64);
#pragma unroll
      for (int qt = 0; qt < 2; ++qt)
#pragma unroll
        for (int r = 0; r < 4; ++r)
          lrun[qt][r] = lrun[qt][r] * alpha[qt][r] + rsum[qt][r];
#pragma unroll
      for (int qt = 0; qt < 2; ++qt)
#pragma unroll
        for (int db = 0; db < 8; ++db)
#pragma unroll
          for (int r = 0; r < 4; ++r) facc[qt][db][r] *= alpha[qt][r];
#pragma unroll
      for (int qt = 0; qt < 2; ++qt)
#pragma unroll
        for (int ks = 0; ks < 4; ++ks)
#pragma unroll
          for (int r = 0; r < 4; ++r)
            Pl[(qt * 16 + l4 * 4 + r) * 72 + ks * 16 + l15] = f2b(sacc[qt][ks][r]);
      asm volatile("s_waitcnt lgkmcnt(0)" ::: "memory");
    }

    if (morek) asm volatile("s_waitcnt vmcnt(4)" ::: "memory");  // V(t) landed; K(t+1) flies
    else       asm volatile("s_waitcnt vmcnt(0)" ::: "memory");
    BARRIER();

    if (active) {
      __builtin_amdgcn_s_setprio(1);
#pragma unroll
      for (int kc2 = 0; kc2 < 2; ++kc2) {
        short8 ap0 = *(const short8*)&Pl[l15 * 72 + kc2 * 32 + l4 * 8];
        short8 ap1 = *(const short8*)&Pl[(16 + l15) * 72 + kc2 * 32 + l4 * 8];
#pragma unroll
        for (int db = 0; db < 8; ++db) {
          const int row = db * 16 + l15;
          short8 bv = *(const short8*)&Vlds[row * 64 + ((kc2 * 32 + l4 * 8) ^ ((row & 7) << 3))];
          facc[0][db] = __builtin_amdgcn_mfma_f32_16x16x32_bf16(ap0, bv, facc[0][db], 0, 0, 0);
          facc[1][db] = __builtin_amdgcn_mfma_f32_16x16x32_bf16(ap1, bv, facc[1][db], 0, 0, 0);
        }
      }
      __builtin_amdgcn_s_setprio(0);
    }
    BARRIER();                     // all waves done reading Vlds
    if (morek) {
#pragma unroll
      for (int g = 0; g < 4; ++g) { gload_lds16(vsrc[g], &Vlds[g * 2048 + dstoff]); vsrc[g] += 64; }
    }
  }
#pragma unroll
  for (int qt = 0; qt < 2; ++qt) {
    u16* Op = O + (size_t)(b * SEQQ + qw + qt * 16) * D_MODEL + h * DK;
    float inv[4];
#pragma unroll
    for (int r = 0; r < 4; ++r) inv[r] = 1.0f / lrun[qt][r];
#pragma unroll
    for (int db = 0; db < 8; ++db)
#pragma unroll
      for (int r = 0; r < 4; ++r)
        Op[(size_t)(l4 * 4 + r) * D_MODEL + db * 16 + l15] = f2b(facc[qt][db][r] * inv[r]);
  }
}

extern "C" void kernel_launch(void* const* d_in, const int* in_sizes, int n_in,
                              void* d_out, int out_size, void* d_ws, size_t ws_size,
                              hipStream_t stream) {
  const float* x   = (const float*)d_in[0];
  const int*   pos = (const int*)d_in[1];
  const float* wq  = (const float*)d_in[2];
  const float* wk  = (const float*)d_in[3];
  const float* wv  = (const float*)d_in[4];
  const float* wo  = (const float*)d_in[5];
  float* out = (float*)d_out;
  char* ws = (char*)d_ws;

  u16* Xb   = (u16*)(ws);                      // 16 MB; reused as AO after QKV GEMM
  u16* Wqkv = (u16*)(ws + (16u << 20));        // 24 MB
  u16* Wob  = (u16*)(ws + (40u << 20));        // 8 MB
  u16* Qb   = (u16*)(ws + (48u << 20));        // 16 MB
  u16* Kb   = (u16*)(ws + (64u << 20));        // 16 MB
  u16* Vt   = (u16*)(ws + (80u << 20));        // 16 MB (transposed V from GEMM)
  u16* AO   = Xb;

  const int nX = MTOT * D_MODEL;

  cvt_bf16<<<nX / 1024, 256, 0, stream>>>(x, Xb, nX / 4);
  cvt_w<<<16384, 256, 0, stream>>>(wq, wk, wv, wo, Wqkv, Wob);

  // fused QKV GEMM: M=4096, N=6144 -> 768 blocks; V written transposed
  gemm8<0><<<768, 512, 0, stream>>>(Xb, Wqkv, Qb, Kb, Vt, nullptr, 96);

  rope_qk<<<32768, 256, 0, stream>>>(Qb, Kb, pos);

  attn_fwd<<<dim3(BATCH * NHEAD, SEQQ / 128), 256, 0, stream>>>(Qb, Kb, Vt, AO);

  // final GEMM: M=4096, N=2048 -> 256 blocks, f32 out
  gemm8<1><<<256, 512, 0, stream>>>(AO, Wob, nullptr, nullptr, nullptr, out, 32);
}

// Round 5
// 301.592 us; speedup vs baseline: 2.6087x; 1.1049x over previous
//
#include <hip/hip_runtime.h>
#include <cstdint>

typedef unsigned short u16;
typedef __attribute__((ext_vector_type(8))) short short8;
typedef __attribute__((ext_vector_type(4))) float f32x4;

#define D_MODEL 2048
#define NHEAD   16
#define DK      128
#define SEQQ    2048
#define BATCH   2
#define MTOT    (BATCH*SEQQ)   // 4096

#define FENCE() asm volatile("" ::: "memory")
#define BARRIER() do { FENCE(); __builtin_amdgcn_s_barrier(); FENCE(); } while (0)

__device__ __forceinline__ u16 f2b(float f) {
  union { float f; uint32_t u; } c; c.f = f;
  uint32_t u = c.u;
  u += 0x7fffu + ((u >> 16) & 1u);
  return (u16)(u >> 16);
}
__device__ __forceinline__ float b2f(u16 h) {
  union { uint32_t u; float f; } c; c.u = ((uint32_t)h) << 16;
  return c.f;
}

__device__ __forceinline__ void gload_lds16(const void* g, void* l) {
  __builtin_amdgcn_global_load_lds(
      (const __attribute__((address_space(1))) void*)(uintptr_t)g,
      (__attribute__((address_space(3))) void*)(uint32_t)(uintptr_t)l,
      16, 0, 0);
}

// ---- DPP 16-lane row reductions (VALU-speed, no ds_bpermute) ----
// steps: xor1 (quad_perm[1,0,3,2]=0xB1), xor2 (quad_perm[2,3,0,1]=0x4E),
// then row_half_mirror (0x141) and row_mirror (0x140) — valid because after
// the first two steps values are quad-uniform / 8-group-uniform.
__device__ __forceinline__ float dpp_max16(float x) {
  float t;
  t = __int_as_float(__builtin_amdgcn_mov_dpp(__float_as_int(x), 0xB1, 0xF, 0xF, true));
  x = fmaxf(x, t);
  t = __int_as_float(__builtin_amdgcn_mov_dpp(__float_as_int(x), 0x4E, 0xF, 0xF, true));
  x = fmaxf(x, t);
  t = __int_as_float(__builtin_amdgcn_mov_dpp(__float_as_int(x), 0x141, 0xF, 0xF, true));
  x = fmaxf(x, t);
  t = __int_as_float(__builtin_amdgcn_mov_dpp(__float_as_int(x), 0x140, 0xF, 0xF, true));
  x = fmaxf(x, t);
  return x;
}
__device__ __forceinline__ float dpp_sum16(float x) {
  float t;
  t = __int_as_float(__builtin_amdgcn_mov_dpp(__float_as_int(x), 0xB1, 0xF, 0xF, true));
  x += t;
  t = __int_as_float(__builtin_amdgcn_mov_dpp(__float_as_int(x), 0x4E, 0xF, 0xF, true));
  x += t;
  t = __int_as_float(__builtin_amdgcn_mov_dpp(__float_as_int(x), 0x141, 0xF, 0xF, true));
  x += t;
  t = __int_as_float(__builtin_amdgcn_mov_dpp(__float_as_int(x), 0x140, 0xF, 0xF, true));
  x += t;
  return x;
}

// ---------------- f32 -> bf16 convert: X ----------------
__global__ __launch_bounds__(256) void cvt_bf16(const float* __restrict__ src,
                                                u16* __restrict__ dst, int n4) {
  int i = blockIdx.x * 256 + threadIdx.x;
  if (i >= n4) return;
  float4 v = ((const float4*)src)[i];
  union { u16 s[4]; uint64_t q; } o;
  o.s[0] = f2b(v.x); o.s[1] = f2b(v.y); o.s[2] = f2b(v.z); o.s[3] = f2b(v.w);
  ((uint64_t*)dst)[i] = o.q;
}

// ---------------- fused weight converts ----------------
__global__ __launch_bounds__(256) void cvt_w(const float* __restrict__ wq,
                                             const float* __restrict__ wk,
                                             const float* __restrict__ wv,
                                             const float* __restrict__ wo,
                                             u16* __restrict__ Wqkv,
                                             u16* __restrict__ Wob) {
  int i = blockIdx.x * 256 + threadIdx.x;
  int which = i >> 20, j = i & 1048575;
  const float* src = (which == 0) ? wq : (which == 1) ? wk : (which == 2) ? wv : wo;
  u16* dst = (which < 3) ? (Wqkv + (size_t)which * 4194304) : Wob;
  float4 v = ((const float4*)src)[j];
  union { u16 s[4]; uint64_t q; } o;
  o.s[0] = f2b(v.x); o.s[1] = f2b(v.y); o.s[2] = f2b(v.z); o.s[3] = f2b(v.w);
  ((uint64_t*)dst)[j] = o.q;
}

// ============ 8-phase-style GEMM: C[M,N] = A[M,2048] * B[N,2048]^T ============
template<int MODE>
__global__ __launch_bounds__(512) void gemm8(const u16* __restrict__ A,
                                             const u16* __restrict__ B,
                                             u16* __restrict__ Cq, u16* __restrict__ Ck,
                                             u16* __restrict__ Vt, float* __restrict__ Cf,
                                             int cpx) {
  __shared__ __align__(16) u16 As[3][128 * 64];
  __shared__ __align__(16) u16 Bs[3][256 * 64];
  const int tid = threadIdx.x;
  const int wave = tid >> 6, lane = tid & 63;
  const int l15 = lane & 15, l4 = lane >> 4;
  const int wr = wave >> 2, wc = wave & 3;
  const int wg = ((int)blockIdx.x & 7) * cpx + ((int)blockIdx.x >> 3);
  const int bm = wg & 31, bn = wg >> 5;
  const int row0 = bm * 128, col0 = bn * 256;

  const u16* asrc[2]; const u16* bsrc[4];
  {
    const int r = tid >> 3, c8 = tid & 7;
#pragma unroll
    for (int p = 0; p < 2; ++p) {
      int row = p * 64 + r;
      asrc[p] = A + (size_t)(row0 + row) * 2048 + ((c8 ^ (row & 7)) << 3);
    }
#pragma unroll
    for (int p = 0; p < 4; ++p) {
      int row = p * 64 + r;
      bsrc[p] = B + (size_t)(col0 + row) * 2048 + ((c8 ^ (row & 7)) << 3);
    }
  }
  const int ldst = wave * 512 + lane * 8;

  int aoff[4][2], boff[4][2];
#pragma unroll
  for (int m = 0; m < 4; ++m) {
    int row = wr * 64 + m * 16 + l15;
#pragma unroll
    for (int ks = 0; ks < 2; ++ks)
      aoff[m][ks] = row * 64 + (((ks * 4 + l4) ^ (l15 & 7)) << 3);
  }
#pragma unroll
  for (int n = 0; n < 4; ++n) {
    int row = wc * 64 + n * 16 + l15;
#pragma unroll
    for (int ks = 0; ks < 2; ++ks)
      boff[n][ks] = row * 64 + (((ks * 4 + l4) ^ (l15 & 7)) << 3);
  }

  f32x4 acc[4][4] = {};

#define STAGE0(slot, kt) do { \
    gload_lds16(asrc[0] + ((kt) << 6), &As[slot][0 * 4096 + ldst]); \
    gload_lds16(asrc[1] + ((kt) << 6), &As[slot][1 * 4096 + ldst]); \
    gload_lds16(bsrc[0] + ((kt) << 6), &Bs[slot][0 * 4096 + ldst]); \
  } while (0)
#define STAGE1(slot, kt) do { \
    gload_lds16(bsrc[1] + ((kt) << 6), &Bs[slot][1 * 4096 + ldst]); \
    gload_lds16(bsrc[2] + ((kt) << 6), &Bs[slot][2 * 4096 + ldst]); \
    gload_lds16(bsrc[3] + ((kt) << 6), &Bs[slot][3 * 4096 + ldst]); \
  } while (0)

  STAGE0(0, 0); STAGE1(0, 0);
  STAGE0(1, 1); STAGE1(1, 1);
  asm volatile("s_waitcnt vmcnt(6)" ::: "memory");
  BARRIER();

  int slot = 0;
  for (int t = 0; t < 32; ++t) {
    const int slot2 = slot ? slot - 1 : 2;
    const bool pf = (t + 2 < 32);
    short8 af[4], bf[4];
#pragma unroll
    for (int m = 0; m < 4; ++m) af[m] = *(const short8*)&As[slot][aoff[m][0]];
#pragma unroll
    for (int n = 0; n < 4; ++n) bf[n] = *(const short8*)&Bs[slot][boff[n][0]];
    if (pf) STAGE0(slot2, t + 2);
    BARRIER();
    __builtin_amdgcn_s_setprio(1);
#pragma unroll
    for (int m = 0; m < 4; ++m)
#pragma unroll
      for (int n = 0; n < 4; ++n)
        acc[m][n] = __builtin_amdgcn_mfma_f32_16x16x32_bf16(af[m], bf[n], acc[m][n], 0, 0, 0);
    __builtin_amdgcn_s_setprio(0);
    BARRIER();
#pragma unroll
    for (int m = 0; m < 4; ++m) af[m] = *(const short8*)&As[slot][aoff[m][1]];
#pragma unroll
    for (int n = 0; n < 4; ++n) bf[n] = *(const short8*)&Bs[slot][boff[n][1]];
    if (pf) STAGE1(slot2, t + 2);
    BARRIER();
    __builtin_amdgcn_s_setprio(1);
#pragma unroll
    for (int m = 0; m < 4; ++m)
#pragma unroll
      for (int n = 0; n < 4; ++n)
        acc[m][n] = __builtin_amdgcn_mfma_f32_16x16x32_bf16(af[m], bf[n], acc[m][n], 0, 0, 0);
    __builtin_amdgcn_s_setprio(0);
    if (pf) asm volatile("s_waitcnt vmcnt(6)" ::: "memory");
    else    asm volatile("s_waitcnt vmcnt(0)" ::: "memory");
    BARRIER();
    slot = (slot == 2) ? 0 : slot + 1;
  }
#undef STAGE0
#undef STAGE1

#pragma unroll
  for (int m = 0; m < 4; ++m) {
    const int row = row0 + wr * 64 + m * 16 + l4 * 4;
#pragma unroll
    for (int n = 0; n < 4; ++n) {
      const int col = wc * 64 + n * 16 + l15;
      if (MODE == 1) {
#pragma unroll
        for (int r = 0; r < 4; ++r)
          Cf[(size_t)(row + r) * 2048 + col0 + col] = acc[m][n][r];
      } else {
        const int region = col0 >> 11;
        const int col2 = (col0 & 2047) + col;
        if (region < 2) {
          u16* Cx = region ? Ck : Cq;
#pragma unroll
          for (int r = 0; r < 4; ++r)
            Cx[(size_t)(row + r) * 2048 + col2] = f2b(acc[m][n][r]);
        } else {
          union { u16 h4[4]; uint64_t q; } pk;
#pragma unroll
          for (int r = 0; r < 4; ++r) pk.h4[r] = f2b(acc[m][n][r]);
          const int bb = row >> 11, ss = row & 2047;
          const int hh = col2 >> 7, dd = col2 & 127;
          *(uint64_t*)&Vt[((size_t)((bb << 4) + hh) * 128 + dd) * 2048 + ss] = pk.q;
        }
      }
    }
  }
}

// ---------------- RoPE in-place, fused Q+K ----------------
__global__ __launch_bounds__(256) void rope_qk(u16* __restrict__ Qb, u16* __restrict__ Kb,
                                               const int* __restrict__ pos) {
  int p = blockIdx.x * 256 + threadIdx.x;
  u16* X = (p >> 22) ? Kb : Qb;
  int pp = p & 4194303;
  int m = pp >> 10, j2 = pp & 1023;
  int h = j2 >> 6, j = j2 & 63;
  int s = m & (SEQQ - 1);
  float fp = (float)pos[s];
  float freq = exp2f((float)j * -0.20762050593046014f);
  float ang = fp * freq;
  float sn, cs;
  sincosf(ang, &sn, &cs);
  u16* px = X + (size_t)m * D_MODEL + h * DK + 2 * j;
  uint32_t pair = *(uint32_t*)px;
  float x1 = b2f((u16)(pair & 0xffff)), x2 = b2f((u16)(pair >> 16));
  u16 r1 = f2b(x1 * cs - x2 * sn);
  u16 r2 = f2b(x1 * sn + x2 * cs);
  *(uint32_t*)px = (uint32_t)r1 | ((uint32_t)r2 << 16);
}

// ---------------- Flash attention (causal), DPP softmax ----------------
__global__ __launch_bounds__(256) void attn_fwd(const u16* __restrict__ Q,
                                                const u16* __restrict__ Kg,
                                                const u16* __restrict__ Vt,
                                                u16* __restrict__ O) {
  __shared__ __align__(16) u16 Klds[2][64 * 128];
  __shared__ __align__(16) u16 Vlds[128 * 64];
  __shared__ __align__(16) u16 Plds[4][32 * 72];
  const int tid = threadIdx.x, wave = tid >> 6, lane = tid & 63;
  const int l15 = lane & 15, l4 = lane >> 4;
  const int bh = blockIdx.x;
  const int bxr = 15 - (int)blockIdx.y;
  const int b = bh >> 4, h = bh & 15;
  const int q0 = bxr * 128, qw = q0 + wave * 32;
  const float qscale = 0.1275174470974136f;      // 1/sqrt(128)*log2(e)

  short8 aq[2][4];
#pragma unroll
  for (int qt = 0; qt < 2; ++qt) {
    const u16* Qp = Q + (size_t)(b * SEQQ + qw + qt * 16 + l15) * D_MODEL + h * DK + l4 * 8;
#pragma unroll
    for (int kc = 0; kc < 4; ++kc) {
      short8 raw = *(const short8*)(Qp + kc * 32);
#pragma unroll
      for (int j = 0; j < 8; ++j) raw[j] = (short)f2b(b2f((u16)raw[j]) * qscale);
      aq[qt][kc] = raw;
    }
  }
  asm volatile("s_waitcnt vmcnt(0)" ::: "memory");   // Q drained: counted waits exact

  f32x4 facc[2][8] = {};
  float mrun[2][4], lpart[2][4];                 // lpart: per-lane partial denominator
#pragma unroll
  for (int qt = 0; qt < 2; ++qt)
#pragma unroll
    for (int r = 0; r < 4; ++r) { mrun[qt][r] = -1e30f; lpart[qt][r] = 0.f; }

  const u16* Kbase = Kg + (size_t)b * SEQQ * D_MODEL + h * DK;
  const u16* Vbase = Vt + (size_t)bh * DK * SEQQ;

  const u16* ksrc[4]; const u16* vsrc[4];
#pragma unroll
  for (int g = 0; g < 4; ++g) {
    int kr = g * 16 + (tid >> 4);
    int kc = ((tid & 15) * 8) ^ ((kr & 7) << 3);
    ksrc[g] = Kbase + (size_t)kr * D_MODEL + kc;
    int vr = g * 32 + (tid >> 3);
    int vc = ((tid & 7) * 8) ^ ((vr & 7) << 3);
    vsrc[g] = Vbase + (size_t)vr * SEQQ + vc;
  }
  const int dstoff = tid * 8;

  const int nkt = 2 * (bxr + 1);
#pragma unroll
  for (int g = 0; g < 4; ++g) { gload_lds16(ksrc[g], &Klds[0][g * 2048 + dstoff]); ksrc[g] += (size_t)64 * D_MODEL; }
#pragma unroll
  for (int g = 0; g < 4; ++g) { gload_lds16(vsrc[g], &Vlds[g * 2048 + dstoff]); vsrc[g] += 64; }

  u16* Pl = Plds[wave];

  for (int kt = 0; kt < nkt; ++kt) {
    const int k0 = kt * 64;
    const int cur = kt & 1;
    const bool morek = (kt + 1 < nkt);
    if (morek) {
#pragma unroll
      for (int g = 0; g < 4; ++g) { gload_lds16(ksrc[g], &Klds[cur ^ 1][g * 2048 + dstoff]); ksrc[g] += (size_t)64 * D_MODEL; }
      asm volatile("s_waitcnt vmcnt(8)" ::: "memory");
    } else {
      asm volatile("s_waitcnt vmcnt(4)" ::: "memory");
    }
    BARRIER();

    const bool active = (k0 <= qw + 31);
    if (active) {
      f32x4 sacc[2][4] = {};
      __builtin_amdgcn_s_setprio(1);
#pragma unroll
      for (int ks = 0; ks < 4; ++ks) {
        const int row = ks * 16 + l15;
        short8 bk[4];
#pragma unroll
        for (int kc = 0; kc < 4; ++kc)
          bk[kc] = *(const short8*)&Klds[cur][row * 128 + ((kc * 32 + l4 * 8) ^ ((row & 7) << 3))];
#pragma unroll
        for (int qt = 0; qt < 2; ++qt)
#pragma unroll
          for (int kc = 0; kc < 4; ++kc)
            sacc[qt][ks] = __builtin_amdgcn_mfma_f32_16x16x32_bf16(aq[qt][kc], bk[kc], sacc[qt][ks], 0, 0, 0);
      }
      __builtin_amdgcn_s_setprio(0);
      // mask + per-lane max
      float pmax[2][4];
#pragma unroll
      for (int qt = 0; qt < 2; ++qt) {
        const int qb = qw + qt * 16;
        const bool dg = (k0 + 63 > qb);
#pragma unroll
        for (int r = 0; r < 4; ++r) pmax[qt][r] = -1e30f;
#pragma unroll
        for (int ks = 0; ks < 4; ++ks)
#pragma unroll
          for (int r = 0; r < 4; ++r) {
            float s = sacc[qt][ks][r];
            if (dg && (k0 + ks * 16 + l15 > qb + l4 * 4 + r)) s = -1e30f;
            sacc[qt][ks][r] = s;
            pmax[qt][r] = fmaxf(pmax[qt][r], s);
          }
      }
      // 16-lane max via DPP (VALU-speed, replaces ds_bpermute shuffles)
#pragma unroll
      for (int qt = 0; qt < 2; ++qt)
#pragma unroll
        for (int r = 0; r < 4; ++r) pmax[qt][r] = dpp_max16(pmax[qt][r]);
      // online softmax; denominator kept as per-lane partial (reduced once at end)
#pragma unroll
      for (int qt = 0; qt < 2; ++qt) {
#pragma unroll
        for (int r = 0; r < 4; ++r) {
          float mn = fmaxf(mrun[qt][r], pmax[qt][r]);
          float alpha = exp2f(mrun[qt][r] - mn);
          mrun[qt][r] = mn;
          float rl = 0.f;
#pragma unroll
          for (int ks = 0; ks < 4; ++ks) {
            float pv = exp2f(sacc[qt][ks][r] - mn);
            sacc[qt][ks][r] = pv;
            rl += pv;
          }
          lpart[qt][r] = lpart[qt][r] * alpha + rl;
#pragma unroll
          for (int db = 0; db < 8; ++db) facc[qt][db][r] *= alpha;
        }
      }
#pragma unroll
      for (int qt = 0; qt < 2; ++qt)
#pragma unroll
        for (int ks = 0; ks < 4; ++ks)
#pragma unroll
          for (int r = 0; r < 4; ++r)
            Pl[(qt * 16 + l4 * 4 + r) * 72 + ks * 16 + l15] = f2b(sacc[qt][ks][r]);
      asm volatile("s_waitcnt lgkmcnt(0)" ::: "memory");
    }

    if (morek) asm volatile("s_waitcnt vmcnt(4)" ::: "memory");
    else       asm volatile("s_waitcnt vmcnt(0)" ::: "memory");
    BARRIER();

    if (active) {
      __builtin_amdgcn_s_setprio(1);
#pragma unroll
      for (int kc2 = 0; kc2 < 2; ++kc2) {
        short8 ap0 = *(const short8*)&Pl[l15 * 72 + kc2 * 32 + l4 * 8];
        short8 ap1 = *(const short8*)&Pl[(16 + l15) * 72 + kc2 * 32 + l4 * 8];
#pragma unroll
        for (int db = 0; db < 8; ++db) {
          const int row = db * 16 + l15;
          short8 bv = *(const short8*)&Vlds[row * 64 + ((kc2 * 32 + l4 * 8) ^ ((row & 7) << 3))];
          facc[0][db] = __builtin_amdgcn_mfma_f32_16x16x32_bf16(ap0, bv, facc[0][db], 0, 0, 0);
          facc[1][db] = __builtin_amdgcn_mfma_f32_16x16x32_bf16(ap1, bv, facc[1][db], 0, 0, 0);
        }
      }
      __builtin_amdgcn_s_setprio(0);
    }
    BARRIER();
    if (morek) {
#pragma unroll
      for (int g = 0; g < 4; ++g) { gload_lds16(vsrc[g], &Vlds[g * 2048 + dstoff]); vsrc[g] += 64; }
    }
  }
  // epilogue: one cross-lane sum for the denominator, then scale+store
#pragma unroll
  for (int qt = 0; qt < 2; ++qt) {
    u16* Op = O + (size_t)(b * SEQQ + qw + qt * 16) * D_MODEL + h * DK;
    float inv[4];
#pragma unroll
    for (int r = 0; r < 4; ++r) inv[r] = 1.0f / dpp_sum16(lpart[qt][r]);
#pragma unroll
    for (int db = 0; db < 8; ++db)
#pragma unroll
      for (int r = 0; r < 4; ++r)
        Op[(size_t)(l4 * 4 + r) * D_MODEL + db * 16 + l15] = f2b(facc[qt][db][r] * inv[r]);
  }
}

extern "C" void kernel_launch(void* const* d_in, const int* in_sizes, int n_in,
                              void* d_out, int out_size, void* d_ws, size_t ws_size,
                              hipStream_t stream) {
  const float* x   = (const float*)d_in[0];
  const int*   pos = (const int*)d_in[1];
  const float* wq  = (const float*)d_in[2];
  const float* wk  = (const float*)d_in[3];
  const float* wv  = (const float*)d_in[4];
  const float* wo  = (const float*)d_in[5];
  float* out = (float*)d_out;
  char* ws = (char*)d_ws;

  u16* Xb   = (u16*)(ws);
  u16* Wqkv = (u16*)(ws + (16u << 20));
  u16* Wob  = (u16*)(ws + (40u << 20));
  u16* Qb   = (u16*)(ws + (48u << 20));
  u16* Kb   = (u16*)(ws + (64u << 20));
  u16* Vt   = (u16*)(ws + (80u << 20));
  u16* AO   = Xb;

  const int nX = MTOT * D_MODEL;

  cvt_bf16<<<nX / 1024, 256, 0, stream>>>(x, Xb, nX / 4);
  cvt_w<<<16384, 256, 0, stream>>>(wq, wk, wv, wo, Wqkv, Wob);

  gemm8<0><<<768, 512, 0, stream>>>(Xb, Wqkv, Qb, Kb, Vt, nullptr, 96);

  rope_qk<<<32768, 256, 0, stream>>>(Qb, Kb, pos);

  attn_fwd<<<dim3(BATCH * NHEAD, SEQQ / 128), 256, 0, stream>>>(Qb, Kb, Vt, AO);

  gemm8<1><<<256, 512, 0, stream>>>(AO, Wob, nullptr, nullptr, nullptr, out, 32);
}

// Round 6
// 276.581 us; speedup vs baseline: 2.8446x; 1.0904x over previous
//
#include <hip/hip_runtime.h>
#include <cstdint>

typedef unsigned short u16;
typedef __attribute__((ext_vector_type(8))) short short8;
typedef __attribute__((ext_vector_type(4))) float f32x4;
typedef __attribute__((ext_vector_type(16))) float f32x16;
typedef __attribute__((ext_vector_type(2))) unsigned int uint2v;

#define D_MODEL 2048
#define NHEAD   16
#define DK      128
#define SEQQ    2048
#define BATCH   2
#define MTOT    (BATCH*SEQQ)   // 4096

#define FENCE() asm volatile("" ::: "memory")
#define BARRIER() do { FENCE(); __builtin_amdgcn_s_barrier(); FENCE(); } while (0)

__device__ __forceinline__ u16 f2b(float f) {
  union { float f; uint32_t u; } c; c.f = f;
  uint32_t u = c.u;
  u += 0x7fffu + ((u >> 16) & 1u);
  return (u16)(u >> 16);
}
__device__ __forceinline__ float b2f(u16 h) {
  union { uint32_t u; float f; } c; c.u = ((uint32_t)h) << 16;
  return c.f;
}

__device__ __forceinline__ void gload_lds16(const void* g, void* l) {
  __builtin_amdgcn_global_load_lds(
      (const __attribute__((address_space(1))) void*)(uintptr_t)g,
      (__attribute__((address_space(3))) void*)(uint32_t)(uintptr_t)l,
      16, 0, 0);
}

// ---------------- f32 -> bf16 convert: X ----------------
__global__ __launch_bounds__(256) void cvt_bf16(const float* __restrict__ src,
                                                u16* __restrict__ dst, int n4) {
  int i = blockIdx.x * 256 + threadIdx.x;
  if (i >= n4) return;
  float4 v = ((const float4*)src)[i];
  union { u16 s[4]; uint64_t q; } o;
  o.s[0] = f2b(v.x); o.s[1] = f2b(v.y); o.s[2] = f2b(v.z); o.s[3] = f2b(v.w);
  ((uint64_t*)dst)[i] = o.q;
}

// ---------------- fused weight converts ----------------
__global__ __launch_bounds__(256) void cvt_w(const float* __restrict__ wq,
                                             const float* __restrict__ wk,
                                             const float* __restrict__ wv,
                                             const float* __restrict__ wo,
                                             u16* __restrict__ Wqkv,
                                             u16* __restrict__ Wob) {
  int i = blockIdx.x * 256 + threadIdx.x;
  int which = i >> 20, j = i & 1048575;
  const float* src = (which == 0) ? wq : (which == 1) ? wk : (which == 2) ? wv : wo;
  u16* dst = (which < 3) ? (Wqkv + (size_t)which * 4194304) : Wob;
  float4 v = ((const float4*)src)[j];
  union { u16 s[4]; uint64_t q; } o;
  o.s[0] = f2b(v.x); o.s[1] = f2b(v.y); o.s[2] = f2b(v.z); o.s[3] = f2b(v.w);
  ((uint64_t*)dst)[j] = o.q;
}

// ============ 8-phase-style GEMM: C[M,N] = A[M,2048] * B[N,2048]^T ============
template<int MODE>
__global__ __launch_bounds__(512) void gemm8(const u16* __restrict__ A,
                                             const u16* __restrict__ B,
                                             u16* __restrict__ Cq, u16* __restrict__ Ck,
                                             u16* __restrict__ Vt, float* __restrict__ Cf,
                                             int cpx) {
  __shared__ __align__(16) u16 As[3][128 * 64];
  __shared__ __align__(16) u16 Bs[3][256 * 64];
  const int tid = threadIdx.x;
  const int wave = tid >> 6, lane = tid & 63;
  const int l15 = lane & 15, l4 = lane >> 4;
  const int wr = wave >> 2, wc = wave & 3;
  const int wg = ((int)blockIdx.x & 7) * cpx + ((int)blockIdx.x >> 3);
  const int bm = wg & 31, bn = wg >> 5;
  const int row0 = bm * 128, col0 = bn * 256;

  const u16* asrc[2]; const u16* bsrc[4];
  {
    const int r = tid >> 3, c8 = tid & 7;
#pragma unroll
    for (int p = 0; p < 2; ++p) {
      int row = p * 64 + r;
      asrc[p] = A + (size_t)(row0 + row) * 2048 + ((c8 ^ (row & 7)) << 3);
    }
#pragma unroll
    for (int p = 0; p < 4; ++p) {
      int row = p * 64 + r;
      bsrc[p] = B + (size_t)(col0 + row) * 2048 + ((c8 ^ (row & 7)) << 3);
    }
  }
  const int ldst = wave * 512 + lane * 8;

  int aoff[4][2], boff[4][2];
#pragma unroll
  for (int m = 0; m < 4; ++m) {
    int row = wr * 64 + m * 16 + l15;
#pragma unroll
    for (int ks = 0; ks < 2; ++ks)
      aoff[m][ks] = row * 64 + (((ks * 4 + l4) ^ (l15 & 7)) << 3);
  }
#pragma unroll
  for (int n = 0; n < 4; ++n) {
    int row = wc * 64 + n * 16 + l15;
#pragma unroll
    for (int ks = 0; ks < 2; ++ks)
      boff[n][ks] = row * 64 + (((ks * 4 + l4) ^ (l15 & 7)) << 3);
  }

  f32x4 acc[4][4] = {};

#define STAGE0(slot, kt) do { \
    gload_lds16(asrc[0] + ((kt) << 6), &As[slot][0 * 4096 + ldst]); \
    gload_lds16(asrc[1] + ((kt) << 6), &As[slot][1 * 4096 + ldst]); \
    gload_lds16(bsrc[0] + ((kt) << 6), &Bs[slot][0 * 4096 + ldst]); \
  } while (0)
#define STAGE1(slot, kt) do { \
    gload_lds16(bsrc[1] + ((kt) << 6), &Bs[slot][1 * 4096 + ldst]); \
    gload_lds16(bsrc[2] + ((kt) << 6), &Bs[slot][2 * 4096 + ldst]); \
    gload_lds16(bsrc[3] + ((kt) << 6), &Bs[slot][3 * 4096 + ldst]); \
  } while (0)

  STAGE0(0, 0); STAGE1(0, 0);
  STAGE0(1, 1); STAGE1(1, 1);
  asm volatile("s_waitcnt vmcnt(6)" ::: "memory");
  BARRIER();

  int slot = 0;
  for (int t = 0; t < 32; ++t) {
    const int slot2 = slot ? slot - 1 : 2;
    const bool pf = (t + 2 < 32);
    short8 af[4], bf[4];
#pragma unroll
    for (int m = 0; m < 4; ++m) af[m] = *(const short8*)&As[slot][aoff[m][0]];
#pragma unroll
    for (int n = 0; n < 4; ++n) bf[n] = *(const short8*)&Bs[slot][boff[n][0]];
    if (pf) STAGE0(slot2, t + 2);
    BARRIER();
    __builtin_amdgcn_s_setprio(1);
#pragma unroll
    for (int m = 0; m < 4; ++m)
#pragma unroll
      for (int n = 0; n < 4; ++n)
        acc[m][n] = __builtin_amdgcn_mfma_f32_16x16x32_bf16(af[m], bf[n], acc[m][n], 0, 0, 0);
    __builtin_amdgcn_s_setprio(0);
    BARRIER();
#pragma unroll
    for (int m = 0; m < 4; ++m) af[m] = *(const short8*)&As[slot][aoff[m][1]];
#pragma unroll
    for (int n = 0; n < 4; ++n) bf[n] = *(const short8*)&Bs[slot][boff[n][1]];
    if (pf) STAGE1(slot2, t + 2);
    BARRIER();
    __builtin_amdgcn_s_setprio(1);
#pragma unroll
    for (int m = 0; m < 4; ++m)
#pragma unroll
      for (int n = 0; n < 4; ++n)
        acc[m][n] = __builtin_amdgcn_mfma_f32_16x16x32_bf16(af[m], bf[n], acc[m][n], 0, 0, 0);
    __builtin_amdgcn_s_setprio(0);
    if (pf) asm volatile("s_waitcnt vmcnt(6)" ::: "memory");
    else    asm volatile("s_waitcnt vmcnt(0)" ::: "memory");
    BARRIER();
    slot = (slot == 2) ? 0 : slot + 1;
  }
#undef STAGE0
#undef STAGE1

#pragma unroll
  for (int m = 0; m < 4; ++m) {
    const int row = row0 + wr * 64 + m * 16 + l4 * 4;
#pragma unroll
    for (int n = 0; n < 4; ++n) {
      const int col = wc * 64 + n * 16 + l15;
      if (MODE == 1) {
#pragma unroll
        for (int r = 0; r < 4; ++r)
          Cf[(size_t)(row + r) * 2048 + col0 + col] = acc[m][n][r];
      } else {
        const int region = col0 >> 11;
        const int col2 = (col0 & 2047) + col;
        if (region < 2) {
          u16* Cx = region ? Ck : Cq;
#pragma unroll
          for (int r = 0; r < 4; ++r)
            Cx[(size_t)(row + r) * 2048 + col2] = f2b(acc[m][n][r]);
        } else {
          union { u16 h4[4]; uint64_t q; } pk;
#pragma unroll
          for (int r = 0; r < 4; ++r) pk.h4[r] = f2b(acc[m][n][r]);
          const int bb = row >> 11, ss = row & 2047;
          const int hh = col2 >> 7, dd = col2 & 127;
          *(uint64_t*)&Vt[((size_t)((bb << 4) + hh) * 128 + dd) * 2048 + ss] = pk.q;
        }
      }
    }
  }
}

// ---------------- RoPE in-place, fused Q+K ----------------
__global__ __launch_bounds__(256) void rope_qk(u16* __restrict__ Qb, u16* __restrict__ Kb,
                                               const int* __restrict__ pos) {
  int p = blockIdx.x * 256 + threadIdx.x;
  u16* X = (p >> 22) ? Kb : Qb;
  int pp = p & 4194303;
  int m = pp >> 10, j2 = pp & 1023;
  int h = j2 >> 6, j = j2 & 63;
  int s = m & (SEQQ - 1);
  float fp = (float)pos[s];
  float freq = exp2f((float)j * -0.20762050593046014f);
  float ang = fp * freq;
  float sn, cs;
  sincosf(ang, &sn, &cs);
  u16* px = X + (size_t)m * D_MODEL + h * DK + 2 * j;
  uint32_t pair = *(uint32_t*)px;
  float x1 = b2f((u16)(pair & 0xffff)), x2 = b2f((u16)(pair >> 16));
  u16 r1 = f2b(x1 * cs - x2 * sn);
  u16 r2 = f2b(x1 * sn + x2 * cs);
  *(uint32_t*)px = (uint32_t)r1 | ((uint32_t)r2 << 16);
}

// ---------------- Flash attention (causal), swapped-QK^T in-register softmax ----------------
// grid (32, 16), 256 thr = 4 waves; wave w handles 32 q rows (q = qw + lane&31).
// St = mfma_32x32x16(K, Q^T): lane owns row q; softmax fully in-register
// (1 permlane32_swap for the cross-half reduce). P repacked to PV B-operand via
// 16 v_cvt_pk_bf16_f32 + 8 permlane32_swap. O accumulated transposed: O^T = V^T P^T.
__global__ __launch_bounds__(256) void attn_fwd(const u16* __restrict__ Q,
                                                const u16* __restrict__ Kg,
                                                const u16* __restrict__ Vt,
                                                u16* __restrict__ O) {
  __shared__ __align__(16) u16 Klds[2][64 * 128];
  __shared__ __align__(16) u16 Vlds[2][128 * 64];
  const int tid = threadIdx.x, wave = tid >> 6, lane = tid & 63;
  const int l31 = lane & 31, l5 = lane >> 5;
  const int bh = blockIdx.x;
  const int bxr = 15 - (int)blockIdx.y;
  const int b = bh >> 4, h = bh & 15;
  const int q0 = bxr * 128, qw = q0 + wave * 32;
  const float qscale = 0.1275174470974136f;      // 1/sqrt(128)*log2(e)

  // Q B-frags: lane needs Q[qw+l31][16*dt + 8*l5 + j], prescaled
  short8 bq[8];
  {
    const u16* Qp = Q + (size_t)(b * SEQQ + qw + l31) * D_MODEL + h * DK + l5 * 8;
#pragma unroll
    for (int dt = 0; dt < 8; ++dt) {
      short8 raw = *(const short8*)(Qp + dt * 16);
#pragma unroll
      for (int j = 0; j < 8; ++j) raw[j] = (short)f2b(b2f((u16)raw[j]) * qscale);
      bq[dt] = raw;
    }
  }
  asm volatile("s_waitcnt vmcnt(0)" ::: "memory");   // drain Q loads

  f32x16 facc[4] = {};           // O^T accumulators, one per 32-d tile
  float mrun = -1e30f, lpart = 0.f;

  const u16* Kbase = Kg + (size_t)b * SEQQ * D_MODEL + h * DK;
  const u16* Vbase = Vt + (size_t)bh * DK * SEQQ;
  const u16* ksrc[4]; const u16* vsrc[4];
#pragma unroll
  for (int g = 0; g < 4; ++g) {
    int kr = g * 16 + (tid >> 4);
    int kc = ((tid & 15) * 8) ^ ((kr & 7) << 3);
    ksrc[g] = Kbase + (size_t)kr * D_MODEL + kc;
    int vr = g * 32 + (tid >> 3);
    int vc = ((tid & 7) * 8) ^ ((vr & 7) << 3);
    vsrc[g] = Vbase + (size_t)vr * SEQQ + vc;
  }
  const int dstoff = tid * 8;
  const int nkt = 2 * (bxr + 1);

  // prologue: K0,V0 into buffer 0
#pragma unroll
  for (int g = 0; g < 4; ++g) { gload_lds16(ksrc[g], &Klds[0][g * 2048 + dstoff]); ksrc[g] += (size_t)64 * D_MODEL; }
#pragma unroll
  for (int g = 0; g < 4; ++g) { gload_lds16(vsrc[g], &Vlds[0][g * 2048 + dstoff]); vsrc[g] += 64; }

  for (int kt = 0; kt < nkt; ++kt) {
    const int k0 = kt * 64, cur = kt & 1;
    asm volatile("s_waitcnt vmcnt(0)" ::: "memory");   // own K(t),V(t) landed
    BARRIER();                                         // => everyone's landed; prev reads done
    if (kt + 1 < nkt) {                                // prefetch next tile into other buffer
#pragma unroll
      for (int g = 0; g < 4; ++g) { gload_lds16(ksrc[g], &Klds[cur ^ 1][g * 2048 + dstoff]); ksrc[g] += (size_t)64 * D_MODEL; }
#pragma unroll
      for (int g = 0; g < 4; ++g) { gload_lds16(vsrc[g], &Vlds[cur ^ 1][g * 2048 + dstoff]); vsrc[g] += 64; }
    }
    if (k0 > qw + 31) continue;                        // fully-masked for this wave

    const u16* Kl = Klds[cur];
    const u16* Vl = Vlds[cur];

    // ---- QK^T (swapped): St[k][q], lane: q=l31, k = 32*ks2 + (r&3)+8*(r>>2)+4*l5
    f32x16 st0 = {}, st1 = {};
    __builtin_amdgcn_s_setprio(1);
#pragma unroll
    for (int dt = 0; dt < 8; ++dt) {
      const int ch = ((2 * dt + l5) ^ (l31 & 7)) * 8;
      short8 ak0 = *(const short8*)&Kl[l31 * 128 + ch];
      short8 ak1 = *(const short8*)&Kl[(32 + l31) * 128 + ch];
      st0 = __builtin_amdgcn_mfma_f32_32x32x16_bf16(ak0, bq[dt], st0, 0, 0, 0);
      st1 = __builtin_amdgcn_mfma_f32_32x32x16_bf16(ak1, bq[dt], st1, 0, 0, 0);
    }
    __builtin_amdgcn_s_setprio(0);

    // ---- causal mask (diag tiles only) ----
    if (k0 + 63 > qw) {
      const int qm = qw + l31 - k0 - 4 * l5;           // mask where kconst > qm
#pragma unroll
      for (int r = 0; r < 16; ++r) {
        const int kc0 = (r & 3) + 8 * (r >> 2);
        st0[r] = (kc0 > qm) ? -1e30f : st0[r];
        st1[r] = (kc0 + 32 > qm) ? -1e30f : st1[r];
      }
    }

    // ---- row max: in-lane tree + one permlane32_swap ----
    float mx[8];
#pragma unroll
    for (int r = 0; r < 8; ++r) mx[r] = fmaxf(fmaxf(st0[r], st0[r + 8]), fmaxf(st1[r], st1[r + 8]));
    float m = fmaxf(fmaxf(fmaxf(mx[0], mx[1]), fmaxf(mx[2], mx[3])),
                    fmaxf(fmaxf(mx[4], mx[5]), fmaxf(mx[6], mx[7])));
    {
      uint2v sw = __builtin_amdgcn_permlane32_swap(__float_as_uint(m), __float_as_uint(m), false, false);
      m = fmaxf(__uint_as_float(sw.x), __uint_as_float(sw.y));
    }
    const float mn = fmaxf(mrun, m);
    const float al = exp2f(mrun - mn);
    mrun = mn;
    float ps = 0.f;
#pragma unroll
    for (int r = 0; r < 16; ++r) { float p = exp2f(st0[r] - mn); st0[r] = p; ps += p; }
#pragma unroll
    for (int r = 0; r < 16; ++r) { float p = exp2f(st1[r] - mn); st1[r] = p; ps += p; }
    lpart = lpart * al + ps;
#pragma unroll
    for (int db = 0; db < 4; ++db) facc[db] *= al;

    // ---- pack P -> PV B-operand: 16 cvt_pk + 8 permlane32_swap ----
    // word C_{a,w} = pk(S[4a+2w], S[4a+2w+1]); swap(C_{2t0,w}, C_{2t0+1,w}) ->
    // (slot w, slot w+2) of pa[2*ks2+t0].
    short8 pa[4];
#pragma unroll
    for (int ks2 = 0; ks2 < 2; ++ks2) {
#pragma unroll
      for (int t0 = 0; t0 < 2; ++t0) {
        uint32_t c0w0, c0w1, c1w0, c1w1;
        if (ks2 == 0) {
          asm("v_cvt_pk_bf16_f32 %0, %1, %2" : "=v"(c0w0) : "v"(st0[8 * t0 + 0]), "v"(st0[8 * t0 + 1]));
          asm("v_cvt_pk_bf16_f32 %0, %1, %2" : "=v"(c0w1) : "v"(st0[8 * t0 + 2]), "v"(st0[8 * t0 + 3]));
          asm("v_cvt_pk_bf16_f32 %0, %1, %2" : "=v"(c1w0) : "v"(st0[8 * t0 + 4]), "v"(st0[8 * t0 + 5]));
          asm("v_cvt_pk_bf16_f32 %0, %1, %2" : "=v"(c1w1) : "v"(st0[8 * t0 + 6]), "v"(st0[8 * t0 + 7]));
        } else {
          asm("v_cvt_pk_bf16_f32 %0, %1, %2" : "=v"(c0w0) : "v"(st1[8 * t0 + 0]), "v"(st1[8 * t0 + 1]));
          asm("v_cvt_pk_bf16_f32 %0, %1, %2" : "=v"(c0w1) : "v"(st1[8 * t0 + 2]), "v"(st1[8 * t0 + 3]));
          asm("v_cvt_pk_bf16_f32 %0, %1, %2" : "=v"(c1w0) : "v"(st1[8 * t0 + 4]), "v"(st1[8 * t0 + 5]));
          asm("v_cvt_pk_bf16_f32 %0, %1, %2" : "=v"(c1w1) : "v"(st1[8 * t0 + 6]), "v"(st1[8 * t0 + 7]));
        }
        uint2v s0 = __builtin_amdgcn_permlane32_swap(c0w0, c1w0, false, false);
        uint2v s1 = __builtin_amdgcn_permlane32_swap(c0w1, c1w1, false, false);
        union { uint32_t w[4]; short8 v; } u;
        u.w[0] = s0.x; u.w[1] = s1.x; u.w[2] = s0.y; u.w[3] = s1.y;
        pa[2 * ks2 + t0] = u.v;
      }
    }

    // ---- PV: O^T += V^T P^T ----
    __builtin_amdgcn_s_setprio(1);
#pragma unroll
    for (int db = 0; db < 4; ++db) {
      const int row = 32 * db + l31;
#pragma unroll
      for (int t = 0; t < 4; ++t) {
        const int ch = ((2 * t + l5) ^ (l31 & 7)) * 8;
        short8 av = *(const short8*)&Vl[row * 64 + ch];
        facc[db] = __builtin_amdgcn_mfma_f32_32x32x16_bf16(av, pa[t], facc[db], 0, 0, 0);
      }
    }
    __builtin_amdgcn_s_setprio(0);
  }

  // ---- epilogue: cross-half denominator sum, scale, packed store ----
  float inv;
  {
    uint2v sw = __builtin_amdgcn_permlane32_swap(__float_as_uint(lpart), __float_as_uint(lpart), false, false);
    inv = 1.0f / (__uint_as_float(sw.x) + __uint_as_float(sw.y));
  }
  u16* Op = O + (size_t)(b * SEQQ + qw + l31) * D_MODEL + h * DK;
#pragma unroll
  for (int db = 0; db < 4; ++db)
#pragma unroll
    for (int a = 0; a < 4; ++a) {
      union { u16 h4[4]; uint64_t q; } pk;
#pragma unroll
      for (int c = 0; c < 4; ++c) pk.h4[c] = f2b(facc[db][4 * a + c] * inv);
      *(uint64_t*)&Op[32 * db + 8 * a + 4 * l5] = pk.q;
    }
}

extern "C" void kernel_launch(void* const* d_in, const int* in_sizes, int n_in,
                              void* d_out, int out_size, void* d_ws, size_t ws_size,
                              hipStream_t stream) {
  const float* x   = (const float*)d_in[0];
  const int*   pos = (const int*)d_in[1];
  const float* wq  = (const float*)d_in[2];
  const float* wk  = (const float*)d_in[3];
  const float* wv  = (const float*)d_in[4];
  const float* wo  = (const float*)d_in[5];
  float* out = (float*)d_out;
  char* ws = (char*)d_ws;

  u16* Xb   = (u16*)(ws);
  u16* Wqkv = (u16*)(ws + (16u << 20));
  u16* Wob  = (u16*)(ws + (40u << 20));
  u16* Qb   = (u16*)(ws + (48u << 20));
  u16* Kb   = (u16*)(ws + (64u << 20));
  u16* Vt   = (u16*)(ws + (80u << 20));
  u16* AO   = Xb;

  const int nX = MTOT * D_MODEL;

  cvt_bf16<<<nX / 1024, 256, 0, stream>>>(x, Xb, nX / 4);
  cvt_w<<<16384, 256, 0, stream>>>(wq, wk, wv, wo, Wqkv, Wob);

  gemm8<0><<<768, 512, 0, stream>>>(Xb, Wqkv, Qb, Kb, Vt, nullptr, 96);

  rope_qk<<<32768, 256, 0, stream>>>(Qb, Kb, pos);

  attn_fwd<<<dim3(BATCH * NHEAD, SEQQ / 128), 256, 0, stream>>>(Qb, Kb, Vt, AO);

  gemm8<1><<<256, 512, 0, stream>>>(AO, Wob, nullptr, nullptr, nullptr, out, 32);
}

// Round 8
// 275.742 us; speedup vs baseline: 2.8532x; 1.0030x over previous
//
#include <hip/hip_runtime.h>
#include <cstdint>

typedef unsigned short u16;
typedef __attribute__((ext_vector_type(8))) short short8;
typedef __attribute__((ext_vector_type(4))) float f32x4;
typedef __attribute__((ext_vector_type(16))) float f32x16;
typedef __attribute__((ext_vector_type(2))) unsigned int uint2v;

#define D_MODEL 2048
#define NHEAD   16
#define DK      128
#define SEQQ    2048
#define BATCH   2
#define MTOT    (BATCH*SEQQ)   // 4096

#define FENCE() asm volatile("" ::: "memory")
#define BARRIER() do { FENCE(); __builtin_amdgcn_s_barrier(); FENCE(); } while (0)

__device__ __forceinline__ u16 f2b(float f) {
  union { float f; uint32_t u; } c; c.f = f;
  uint32_t u = c.u;
  u += 0x7fffu + ((u >> 16) & 1u);
  return (u16)(u >> 16);
}
__device__ __forceinline__ float b2f(u16 h) {
  union { uint32_t u; float f; } c; c.u = ((uint32_t)h) << 16;
  return c.f;
}

__device__ __forceinline__ void gload_lds16(const void* g, void* l) {
  __builtin_amdgcn_global_load_lds(
      (const __attribute__((address_space(1))) void*)(uintptr_t)g,
      (__attribute__((address_space(3))) void*)(uint32_t)(uintptr_t)l,
      16, 0, 0);
}

// ---------------- f32 -> bf16 convert: X ----------------
__global__ __launch_bounds__(256) void cvt_bf16(const float* __restrict__ src,
                                                u16* __restrict__ dst, int n4) {
  int i = blockIdx.x * 256 + threadIdx.x;
  if (i >= n4) return;
  float4 v = ((const float4*)src)[i];
  union { u16 s[4]; uint64_t q; } o;
  o.s[0] = f2b(v.x); o.s[1] = f2b(v.y); o.s[2] = f2b(v.z); o.s[3] = f2b(v.w);
  ((uint64_t*)dst)[i] = o.q;
}

// ---------------- fused weight converts ----------------
__global__ __launch_bounds__(256) void cvt_w(const float* __restrict__ wq,
                                             const float* __restrict__ wk,
                                             const float* __restrict__ wv,
                                             const float* __restrict__ wo,
                                             u16* __restrict__ Wqkv,
                                             u16* __restrict__ Wob) {
  int i = blockIdx.x * 256 + threadIdx.x;
  int which = i >> 20, j = i & 1048575;
  const float* src = (which == 0) ? wq : (which == 1) ? wk : (which == 2) ? wv : wo;
  u16* dst = (which < 3) ? (Wqkv + (size_t)which * 4194304) : Wob;
  float4 v = ((const float4*)src)[j];
  union { u16 s[4]; uint64_t q; } o;
  o.s[0] = f2b(v.x); o.s[1] = f2b(v.y); o.s[2] = f2b(v.z); o.s[3] = f2b(v.w);
  ((uint64_t*)dst)[j] = o.q;
}

// ============ GEMM, 1-barrier-per-K-tile double-buffered schedule ============
// C[M,N] = A[M,2048] * B[N,2048]^T. BN=256 always; BM = MF*32 (MF m-frags/wave).
// 512 thr = 8 waves (2 x 4): wave out (MF*16) x 64. acc[MF][4] f32x4.
// Per K-tile: __syncthreads (drains prefetch issued a full tile ago -> free),
// issue next tile's gload_lds into idle buffer, B-frags -> regs once,
// MF/2 phases x 16 MFMA with setprio.
// MODE 0: Q/K bf16 row-major + V transposed -> Vt[bh][d][s]. MODE 1: f32 out.
template<int MF, int MODE>
__global__ __launch_bounds__(512) void gemmT(const u16* __restrict__ A,
                                             const u16* __restrict__ B,
                                             u16* __restrict__ Cq, u16* __restrict__ Ck,
                                             u16* __restrict__ Vt, float* __restrict__ Cf,
                                             int nbm, int cpx) {
  constexpr int BM = MF * 32;
  constexpr int AG = BM / 64;                    // A staging groups
  __shared__ __align__(16) u16 As[2][BM * 64];
  __shared__ __align__(16) u16 Bs[2][256 * 64];
  const int tid = threadIdx.x;
  const int wave = tid >> 6, lane = tid & 63;
  const int l15 = lane & 15, l4 = lane >> 4;
  const int wr = wave >> 2, wc = wave & 3;
  const int wg = ((int)blockIdx.x & 7) * cpx + ((int)blockIdx.x >> 3);  // XCD swizzle
  const int bm = wg % nbm, bn = wg / nbm;        // bm fastest -> B-panel L2 reuse
  const int row0 = bm * BM, col0 = bn * 256;

  // staging sources: pre-swizzled global cols (linear LDS dest, rule #21)
  const u16* asrc[AG]; const u16* bsrc[4];
  {
    const int r = tid >> 3, c8 = tid & 7;
#pragma unroll
    for (int g = 0; g < AG; ++g) {
      int row = g * 64 + r;
      asrc[g] = A + (size_t)(row0 + row) * 2048 + ((c8 ^ (row & 7)) << 3);
    }
#pragma unroll
    for (int g = 0; g < 4; ++g) {
      int row = g * 64 + r;
      bsrc[g] = B + (size_t)(col0 + row) * 2048 + ((c8 ^ (row & 7)) << 3);
    }
  }
  const int ldst = tid * 8;

  // ds_read fragment offsets (swizzled)
  int aoff[MF][2], boff[4][2];
#pragma unroll
  for (int m = 0; m < MF; ++m) {
    int row = wr * (MF * 16) + m * 16 + l15;
#pragma unroll
    for (int ks = 0; ks < 2; ++ks)
      aoff[m][ks] = row * 64 + (((ks * 4 + l4) ^ (l15 & 7)) << 3);
  }
#pragma unroll
  for (int n = 0; n < 4; ++n) {
    int row = wc * 64 + n * 16 + l15;
#pragma unroll
    for (int ks = 0; ks < 2; ++ks)
      boff[n][ks] = row * 64 + (((ks * 4 + l4) ^ (l15 & 7)) << 3);
  }

  f32x4 acc[MF][4] = {};

  // prologue: stage tile 0
  {
#pragma unroll
    for (int g = 0; g < AG; ++g) gload_lds16(asrc[g], &As[0][g * 4096 + ldst]);
#pragma unroll
    for (int g = 0; g < 4; ++g)  gload_lds16(bsrc[g], &Bs[0][g * 4096 + ldst]);
  }

  for (int t = 0; t < 32; ++t) {
    const int buf = t & 1;
    __syncthreads();               // tile t landed (issued a full tile ago: free drain)
    if (t + 1 < 32) {              // prefetch t+1 into idle buffer
#pragma unroll
      for (int g = 0; g < AG; ++g) gload_lds16(asrc[g] + ((t + 1) << 6), &As[buf ^ 1][g * 4096 + ldst]);
#pragma unroll
      for (int g = 0; g < 4; ++g)  gload_lds16(bsrc[g] + ((t + 1) << 6), &Bs[buf ^ 1][g * 4096 + ldst]);
    }
    // B-frags once per tile, held in regs across all phases
    short8 bfr[4][2];
#pragma unroll
    for (int n = 0; n < 4; ++n)
#pragma unroll
      for (int ks = 0; ks < 2; ++ks)
        bfr[n][ks] = *(const short8*)&Bs[buf][boff[n][ks]];
    // MF/2 phases of 16 MFMA (m-pair x 4n x 2ks)
#pragma unroll
    for (int p = 0; p < MF / 2; ++p) {
      short8 a0[2], a1[2];
#pragma unroll
      for (int ks = 0; ks < 2; ++ks) {
        a0[ks] = *(const short8*)&As[buf][aoff[2 * p][ks]];
        a1[ks] = *(const short8*)&As[buf][aoff[2 * p + 1][ks]];
      }
      __builtin_amdgcn_s_setprio(1);
#pragma unroll
      for (int n = 0; n < 4; ++n)
#pragma unroll
        for (int ks = 0; ks < 2; ++ks) {
          acc[2 * p][n]     = __builtin_amdgcn_mfma_f32_16x16x32_bf16(a0[ks], bfr[n][ks], acc[2 * p][n], 0, 0, 0);
          acc[2 * p + 1][n] = __builtin_amdgcn_mfma_f32_16x16x32_bf16(a1[ks], bfr[n][ks], acc[2 * p + 1][n], 0, 0, 0);
        }
      __builtin_amdgcn_s_setprio(0);
    }
  }

  // epilogue
#pragma unroll
  for (int m = 0; m < MF; ++m) {
    const int row = row0 + wr * (MF * 16) + m * 16 + l4 * 4;
#pragma unroll
    for (int n = 0; n < 4; ++n) {
      const int col = wc * 64 + n * 16 + l15;
      if (MODE == 1) {
#pragma unroll
        for (int r = 0; r < 4; ++r)
          Cf[(size_t)(row + r) * 2048 + col0 + col] = acc[m][n][r];
      } else {
        const int region = col0 >> 11;
        const int col2 = (col0 & 2047) + col;
        if (region < 2) {
          u16* Cx = region ? Ck : Cq;
#pragma unroll
          for (int r = 0; r < 4; ++r)
            Cx[(size_t)(row + r) * 2048 + col2] = f2b(acc[m][n][r]);
        } else {
          union { u16 h4[4]; uint64_t q; } pk;
#pragma unroll
          for (int r = 0; r < 4; ++r) pk.h4[r] = f2b(acc[m][n][r]);
          const int bb = row >> 11, ss = row & 2047;
          const int hh = col2 >> 7, dd = col2 & 127;
          *(uint64_t*)&Vt[((size_t)((bb << 4) + hh) * 128 + dd) * 2048 + ss] = pk.q;
        }
      }
    }
  }
}

// ---------------- RoPE in-place, fused Q+K ----------------
__global__ __launch_bounds__(256) void rope_qk(u16* __restrict__ Qb, u16* __restrict__ Kb,
                                               const int* __restrict__ pos) {
  int p = blockIdx.x * 256 + threadIdx.x;
  u16* X = (p >> 22) ? Kb : Qb;
  int pp = p & 4194303;
  int m = pp >> 10, j2 = pp & 1023;
  int h = j2 >> 6, j = j2 & 63;
  int s = m & (SEQQ - 1);
  float fp = (float)pos[s];
  float freq = exp2f((float)j * -0.20762050593046014f);
  float ang = fp * freq;
  float sn, cs;
  sincosf(ang, &sn, &cs);
  u16* px = X + (size_t)m * D_MODEL + h * DK + 2 * j;
  uint32_t pair = *(uint32_t*)px;
  float x1 = b2f((u16)(pair & 0xffff)), x2 = b2f((u16)(pair >> 16));
  u16 r1 = f2b(x1 * cs - x2 * sn);
  u16 r2 = f2b(x1 * sn + x2 * cs);
  *(uint32_t*)px = (uint32_t)r1 | ((uint32_t)r2 << 16);
}

// ---------------- Flash attention (causal), swapped-QK^T in-register softmax ----------------
__global__ __launch_bounds__(256) void attn_fwd(const u16* __restrict__ Q,
                                                const u16* __restrict__ Kg,
                                                const u16* __restrict__ Vt,
                                                u16* __restrict__ O) {
  __shared__ __align__(16) u16 Klds[2][64 * 128];
  __shared__ __align__(16) u16 Vlds[2][128 * 64];
  const int tid = threadIdx.x, wave = tid >> 6, lane = tid & 63;
  const int l31 = lane & 31, l5 = lane >> 5;
  const int bh = blockIdx.x;
  const int bxr = 15 - (int)blockIdx.y;
  const int b = bh >> 4, h = bh & 15;
  const int q0 = bxr * 128, qw = q0 + wave * 32;
  const float qscale = 0.1275174470974136f;      // 1/sqrt(128)*log2(e)

  short8 bq[8];
  {
    const u16* Qp = Q + (size_t)(b * SEQQ + qw + l31) * D_MODEL + h * DK + l5 * 8;
#pragma unroll
    for (int dt = 0; dt < 8; ++dt) {
      short8 raw = *(const short8*)(Qp + dt * 16);
#pragma unroll
      for (int j = 0; j < 8; ++j) raw[j] = (short)f2b(b2f((u16)raw[j]) * qscale);
      bq[dt] = raw;
    }
  }
  asm volatile("s_waitcnt vmcnt(0)" ::: "memory");

  f32x16 facc[4] = {};
  float mrun = -1e30f, lpart = 0.f;

  const u16* Kbase = Kg + (size_t)b * SEQQ * D_MODEL + h * DK;
  const u16* Vbase = Vt + (size_t)bh * DK * SEQQ;
  const u16* ksrc[4]; const u16* vsrc[4];
#pragma unroll
  for (int g = 0; g < 4; ++g) {
    int kr = g * 16 + (tid >> 4);
    int kc = ((tid & 15) * 8) ^ ((kr & 7) << 3);
    ksrc[g] = Kbase + (size_t)kr * D_MODEL + kc;
    int vr = g * 32 + (tid >> 3);
    int vc = ((tid & 7) * 8) ^ ((vr & 7) << 3);
    vsrc[g] = Vbase + (size_t)vr * SEQQ + vc;
  }
  const int dstoff = tid * 8;
  const int nkt = 2 * (bxr + 1);

#pragma unroll
  for (int g = 0; g < 4; ++g) { gload_lds16(ksrc[g], &Klds[0][g * 2048 + dstoff]); ksrc[g] += (size_t)64 * D_MODEL; }
#pragma unroll
  for (int g = 0; g < 4; ++g) { gload_lds16(vsrc[g], &Vlds[0][g * 2048 + dstoff]); vsrc[g] += 64; }

  for (int kt = 0; kt < nkt; ++kt) {
    const int k0 = kt * 64, cur = kt & 1;
    asm volatile("s_waitcnt vmcnt(0)" ::: "memory");
    BARRIER();
    if (kt + 1 < nkt) {
#pragma unroll
      for (int g = 0; g < 4; ++g) { gload_lds16(ksrc[g], &Klds[cur ^ 1][g * 2048 + dstoff]); ksrc[g] += (size_t)64 * D_MODEL; }
#pragma unroll
      for (int g = 0; g < 4; ++g) { gload_lds16(vsrc[g], &Vlds[cur ^ 1][g * 2048 + dstoff]); vsrc[g] += 64; }
    }
    if (k0 > qw + 31) continue;

    const u16* Kl = Klds[cur];
    const u16* Vl = Vlds[cur];

    f32x16 st0 = {}, st1 = {};
    __builtin_amdgcn_s_setprio(1);
#pragma unroll
    for (int dt = 0; dt < 8; ++dt) {
      const int ch = ((2 * dt + l5) ^ (l31 & 7)) * 8;
      short8 ak0 = *(const short8*)&Kl[l31 * 128 + ch];
      short8 ak1 = *(const short8*)&Kl[(32 + l31) * 128 + ch];
      st0 = __builtin_amdgcn_mfma_f32_32x32x16_bf16(ak0, bq[dt], st0, 0, 0, 0);
      st1 = __builtin_amdgcn_mfma_f32_32x32x16_bf16(ak1, bq[dt], st1, 0, 0, 0);
    }
    __builtin_amdgcn_s_setprio(0);

    if (k0 + 63 > qw) {
      const int qm = qw + l31 - k0 - 4 * l5;
#pragma unroll
      for (int r = 0; r < 16; ++r) {
        const int kc0 = (r & 3) + 8 * (r >> 2);
        st0[r] = (kc0 > qm) ? -1e30f : st0[r];
        st1[r] = (kc0 + 32 > qm) ? -1e30f : st1[r];
      }
    }

    float mx[8];
#pragma unroll
    for (int r = 0; r < 8; ++r) mx[r] = fmaxf(fmaxf(st0[r], st0[r + 8]), fmaxf(st1[r], st1[r + 8]));
    float m = fmaxf(fmaxf(fmaxf(mx[0], mx[1]), fmaxf(mx[2], mx[3])),
                    fmaxf(fmaxf(mx[4], mx[5]), fmaxf(mx[6], mx[7])));
    {
      uint2v sw = __builtin_amdgcn_permlane32_swap(__float_as_uint(m), __float_as_uint(m), false, false);
      m = fmaxf(__uint_as_float(sw.x), __uint_as_float(sw.y));
    }
    const float mn = fmaxf(mrun, m);
    const float al = exp2f(mrun - mn);
    mrun = mn;
    float ps = 0.f;
#pragma unroll
    for (int r = 0; r < 16; ++r) { float p = exp2f(st0[r] - mn); st0[r] = p; ps += p; }
#pragma unroll
    for (int r = 0; r < 16; ++r) { float p = exp2f(st1[r] - mn); st1[r] = p; ps += p; }
    lpart = lpart * al + ps;
#pragma unroll
    for (int db = 0; db < 4; ++db) facc[db] *= al;

    short8 pa[4];
#pragma unroll
    for (int ks2 = 0; ks2 < 2; ++ks2) {
#pragma unroll
      for (int t0 = 0; t0 < 2; ++t0) {
        uint32_t c0w0, c0w1, c1w0, c1w1;
        if (ks2 == 0) {
          asm("v_cvt_pk_bf16_f32 %0, %1, %2" : "=v"(c0w0) : "v"(st0[8 * t0 + 0]), "v"(st0[8 * t0 + 1]));
          asm("v_cvt_pk_bf16_f32 %0, %1, %2" : "=v"(c0w1) : "v"(st0[8 * t0 + 2]), "v"(st0[8 * t0 + 3]));
          asm("v_cvt_pk_bf16_f32 %0, %1, %2" : "=v"(c1w0) : "v"(st0[8 * t0 + 4]), "v"(st0[8 * t0 + 5]));
          asm("v_cvt_pk_bf16_f32 %0, %1, %2" : "=v"(c1w1) : "v"(st0[8 * t0 + 6]), "v"(st0[8 * t0 + 7]));
        } else {
          asm("v_cvt_pk_bf16_f32 %0, %1, %2" : "=v"(c0w0) : "v"(st1[8 * t0 + 0]), "v"(st1[8 * t0 + 1]));
          asm("v_cvt_pk_bf16_f32 %0, %1, %2" : "=v"(c0w1) : "v"(st1[8 * t0 + 2]), "v"(st1[8 * t0 + 3]));
          asm("v_cvt_pk_bf16_f32 %0, %1, %2" : "=v"(c1w0) : "v"(st1[8 * t0 + 4]), "v"(st1[8 * t0 + 5]));
          asm("v_cvt_pk_bf16_f32 %0, %1, %2" : "=v"(c1w1) : "v"(st1[8 * t0 + 6]), "v"(st1[8 * t0 + 7]));
        }
        uint2v s0 = __builtin_amdgcn_permlane32_swap(c0w0, c1w0, false, false);
        uint2v s1 = __builtin_amdgcn_permlane32_swap(c0w1, c1w1, false, false);
        union { uint32_t w[4]; short8 v; } u;
        u.w[0] = s0.x; u.w[1] = s1.x; u.w[2] = s0.y; u.w[3] = s1.y;
        pa[2 * ks2 + t0] = u.v;
      }
    }

    __builtin_amdgcn_s_setprio(1);
#pragma unroll
    for (int db = 0; db < 4; ++db) {
      const int row = 32 * db + l31;
#pragma unroll
      for (int t = 0; t < 4; ++t) {
        const int ch = ((2 * t + l5) ^ (l31 & 7)) * 8;
        short8 av = *(const short8*)&Vl[row * 64 + ch];
        facc[db] = __builtin_amdgcn_mfma_f32_32x32x16_bf16(av, pa[t], facc[db], 0, 0, 0);
      }
    }
    __builtin_amdgcn_s_setprio(0);
  }

  float inv;
  {
    uint2v sw = __builtin_amdgcn_permlane32_swap(__float_as_uint(lpart), __float_as_uint(lpart), false, false);
    inv = 1.0f / (__uint_as_float(sw.x) + __uint_as_float(sw.y));
  }
  u16* Op = O + (size_t)(b * SEQQ + qw + l31) * D_MODEL + h * DK;
#pragma unroll
  for (int db = 0; db < 4; ++db)
#pragma unroll
    for (int a = 0; a < 4; ++a) {
      union { u16 h4[4]; uint64_t q; } pk;
#pragma unroll
      for (int c = 0; c < 4; ++c) pk.h4[c] = f2b(facc[db][4 * a + c] * inv);
      *(uint64_t*)&Op[32 * db + 8 * a + 4 * l5] = pk.q;
    }
}

extern "C" void kernel_launch(void* const* d_in, const int* in_sizes, int n_in,
                              void* d_out, int out_size, void* d_ws, size_t ws_size,
                              hipStream_t stream) {
  const float* x   = (const float*)d_in[0];
  const int*   pos = (const int*)d_in[1];
  const float* wq  = (const float*)d_in[2];
  const float* wk  = (const float*)d_in[3];
  const float* wv  = (const float*)d_in[4];
  const float* wo  = (const float*)d_in[5];
  float* out = (float*)d_out;
  char* ws = (char*)d_ws;

  u16* Xb   = (u16*)(ws);
  u16* Wqkv = (u16*)(ws + (16u << 20));
  u16* Wob  = (u16*)(ws + (40u << 20));
  u16* Qb   = (u16*)(ws + (48u << 20));
  u16* Kb   = (u16*)(ws + (64u << 20));
  u16* Vt   = (u16*)(ws + (80u << 20));
  u16* AO   = Xb;

  const int nX = MTOT * D_MODEL;

  cvt_bf16<<<nX / 1024, 256, 0, stream>>>(x, Xb, nX / 4);
  cvt_w<<<16384, 256, 0, stream>>>(wq, wk, wv, wo, Wqkv, Wob);

  // fused QKV GEMM: 256^2 tiles, grid 16x24=384 (bm fastest), cpx=48
  gemmT<8, 0><<<384, 512, 0, stream>>>(Xb, Wqkv, Qb, Kb, Vt, nullptr, 16, 48);

  rope_qk<<<32768, 256, 0, stream>>>(Qb, Kb, pos);

  attn_fwd<<<dim3(BATCH * NHEAD, SEQQ / 128), 256, 0, stream>>>(Qb, Kb, Vt, AO);

  // final GEMM: 128x256 tiles, grid 32x8=256, f32 out, cpx=32
  gemmT<4, 1><<<256, 512, 0, stream>>>(AO, Wob, nullptr, nullptr, nullptr, out, 32, 32);
}

// Round 9
// 271.817 us; speedup vs baseline: 2.8944x; 1.0144x over previous
//
#include <hip/hip_runtime.h>
#include <cstdint>

typedef unsigned short u16;
typedef __attribute__((ext_vector_type(8))) short short8;
typedef __attribute__((ext_vector_type(4))) float f32x4;
typedef __attribute__((ext_vector_type(16))) float f32x16;
typedef __attribute__((ext_vector_type(2))) unsigned int uint2v;

#define D_MODEL 2048
#define NHEAD   16
#define DK      128
#define SEQQ    2048
#define BATCH   2
#define MTOT    (BATCH*SEQQ)   // 4096

#define FENCE() asm volatile("" ::: "memory")
#define BARRIER() do { FENCE(); __builtin_amdgcn_s_barrier(); FENCE(); } while (0)

__device__ __forceinline__ u16 f2b(float f) {
  union { float f; uint32_t u; } c; c.f = f;
  uint32_t u = c.u;
  u += 0x7fffu + ((u >> 16) & 1u);
  return (u16)(u >> 16);
}
__device__ __forceinline__ float b2f(u16 h) {
  union { uint32_t u; float f; } c; c.u = ((uint32_t)h) << 16;
  return c.f;
}

__device__ __forceinline__ void gload_lds16(const void* g, void* l) {
  __builtin_amdgcn_global_load_lds(
      (const __attribute__((address_space(1))) void*)(uintptr_t)g,
      (__attribute__((address_space(3))) void*)(uint32_t)(uintptr_t)l,
      16, 0, 0);
}

// ---------------- f32 -> bf16 convert: X ----------------
__global__ __launch_bounds__(256) void cvt_bf16(const float* __restrict__ src,
                                                u16* __restrict__ dst, int n4) {
  int i = blockIdx.x * 256 + threadIdx.x;
  if (i >= n4) return;
  float4 v = ((const float4*)src)[i];
  union { u16 s[4]; uint64_t q; } o;
  o.s[0] = f2b(v.x); o.s[1] = f2b(v.y); o.s[2] = f2b(v.z); o.s[3] = f2b(v.w);
  ((uint64_t*)dst)[i] = o.q;
}

// ---------------- fused weight converts ----------------
__global__ __launch_bounds__(256) void cvt_w(const float* __restrict__ wq,
                                             const float* __restrict__ wk,
                                             const float* __restrict__ wv,
                                             const float* __restrict__ wo,
                                             u16* __restrict__ Wqkv,
                                             u16* __restrict__ Wob) {
  int i = blockIdx.x * 256 + threadIdx.x;
  int which = i >> 20, j = i & 1048575;
  const float* src = (which == 0) ? wq : (which == 1) ? wk : (which == 2) ? wv : wo;
  u16* dst = (which < 3) ? (Wqkv + (size_t)which * 4194304) : Wob;
  float4 v = ((const float4*)src)[j];
  union { u16 s[4]; uint64_t q; } o;
  o.s[0] = f2b(v.x); o.s[1] = f2b(v.y); o.s[2] = f2b(v.z); o.s[3] = f2b(v.w);
  ((uint64_t*)dst)[j] = o.q;
}

// ============ GEMM, 1-barrier-per-K-tile double-buffered schedule ============
// C[M,N] = A[M,2048] * B[N,2048]^T. BM = MF*32, BN = NF*64.
// 512 thr = 8 waves (2 x 4): wave out (MF*16) x (NF*16). acc[MF][NF] f32x4.
// Per K-tile: __syncthreads (drains prefetch issued a full tile ago),
// prefetch next tile into idle buffer, all frags -> regs, ks-outer MFMA block
// (same-acc dependency distance = MF*NF >= 12).
// MODE 0: Q/K bf16 row-major + V transposed -> Vt[bh][d][s]. MODE 1: f32 out.
template<int MF, int NF, int MODE>
__global__ __launch_bounds__(512) void gemmT(const u16* __restrict__ A,
                                             const u16* __restrict__ B,
                                             u16* __restrict__ Cq, u16* __restrict__ Ck,
                                             u16* __restrict__ Vt, float* __restrict__ Cf,
                                             int nbm, int cpx) {
  constexpr int BM = MF * 32;
  constexpr int BN = NF * 64;
  constexpr int AG = BM / 64;                    // A staging groups (64 rows each)
  constexpr int BG = NF;                         // B staging groups
  __shared__ __align__(16) u16 As[2][BM * 64];
  __shared__ __align__(16) u16 Bs[2][BN * 64];
  const int tid = threadIdx.x;
  const int wave = tid >> 6, lane = tid & 63;
  const int l15 = lane & 15, l4 = lane >> 4;
  const int wr = wave >> 2, wc = wave & 3;
  const int wg = ((int)blockIdx.x & 7) * cpx + ((int)blockIdx.x >> 3);  // XCD swizzle
  const int bm = wg % nbm, bn = wg / nbm;        // bm fastest -> B-panel L2 reuse
  const int row0 = bm * BM, col0 = bn * BN;

  // staging sources: pre-swizzled global cols (linear LDS dest, rule #21)
  const u16* asrc[AG]; const u16* bsrc[BG];
  {
    const int r = tid >> 3, c8 = tid & 7;
#pragma unroll
    for (int g = 0; g < AG; ++g) {
      int row = g * 64 + r;
      asrc[g] = A + (size_t)(row0 + row) * 2048 + ((c8 ^ (row & 7)) << 3);
    }
#pragma unroll
    for (int g = 0; g < BG; ++g) {
      int row = g * 64 + r;
      bsrc[g] = B + (size_t)(col0 + row) * 2048 + ((c8 ^ (row & 7)) << 3);
    }
  }
  const int ldst = tid * 8;

  // ds_read fragment offsets (swizzled)
  int aoff[MF][2], boff[NF][2];
#pragma unroll
  for (int m = 0; m < MF; ++m) {
    int row = wr * (MF * 16) + m * 16 + l15;
#pragma unroll
    for (int ks = 0; ks < 2; ++ks)
      aoff[m][ks] = row * 64 + (((ks * 4 + l4) ^ (l15 & 7)) << 3);
  }
#pragma unroll
  for (int n = 0; n < NF; ++n) {
    int row = wc * (NF * 16) + n * 16 + l15;
#pragma unroll
    for (int ks = 0; ks < 2; ++ks)
      boff[n][ks] = row * 64 + (((ks * 4 + l4) ^ (l15 & 7)) << 3);
  }

  f32x4 acc[MF][NF] = {};

  // prologue: stage tile 0
#pragma unroll
  for (int g = 0; g < AG; ++g) gload_lds16(asrc[g], &As[0][g * 4096 + ldst]);
#pragma unroll
  for (int g = 0; g < BG; ++g) gload_lds16(bsrc[g], &Bs[0][g * 4096 + ldst]);

  for (int t = 0; t < 32; ++t) {
    const int buf = t & 1;
    __syncthreads();               // tile t landed (issued a full tile ago)
    if (t + 1 < 32) {              // prefetch t+1 into idle buffer
#pragma unroll
      for (int g = 0; g < AG; ++g) gload_lds16(asrc[g] + ((t + 1) << 6), &As[buf ^ 1][g * 4096 + ldst]);
#pragma unroll
      for (int g = 0; g < BG; ++g) gload_lds16(bsrc[g] + ((t + 1) << 6), &Bs[buf ^ 1][g * 4096 + ldst]);
    }
    // all fragments -> regs once per tile
    short8 bfr[NF][2], afr[MF][2];
#pragma unroll
    for (int n = 0; n < NF; ++n)
#pragma unroll
      for (int ks = 0; ks < 2; ++ks)
        bfr[n][ks] = *(const short8*)&Bs[buf][boff[n][ks]];
#pragma unroll
    for (int m = 0; m < MF; ++m)
#pragma unroll
      for (int ks = 0; ks < 2; ++ks)
        afr[m][ks] = *(const short8*)&As[buf][aoff[m][ks]];
    // ks-outer MFMA block: dependency distance = MF*NF
    __builtin_amdgcn_s_setprio(1);
#pragma unroll
    for (int ks = 0; ks < 2; ++ks)
#pragma unroll
      for (int n = 0; n < NF; ++n)
#pragma unroll
        for (int m = 0; m < MF; ++m)
          acc[m][n] = __builtin_amdgcn_mfma_f32_16x16x32_bf16(afr[m][ks], bfr[n][ks], acc[m][n], 0, 0, 0);
    __builtin_amdgcn_s_setprio(0);
  }

  // epilogue
#pragma unroll
  for (int m = 0; m < MF; ++m) {
    const int row = row0 + wr * (MF * 16) + m * 16 + l4 * 4;
#pragma unroll
    for (int n = 0; n < NF; ++n) {
      const int col = col0 + wc * (NF * 16) + n * 16 + l15;
      if (MODE == 1) {
#pragma unroll
        for (int r = 0; r < 4; ++r)
          Cf[(size_t)(row + r) * 2048 + col] = acc[m][n][r];
      } else {
        const int region = col >> 11;              // 16-col frags never straddle 2048
        const int col2 = col & 2047;
        if (region < 2) {
          u16* Cx = region ? Ck : Cq;
#pragma unroll
          for (int r = 0; r < 4; ++r)
            Cx[(size_t)(row + r) * 2048 + col2] = f2b(acc[m][n][r]);
        } else {
          union { u16 h4[4]; uint64_t q; } pk;
#pragma unroll
          for (int r = 0; r < 4; ++r) pk.h4[r] = f2b(acc[m][n][r]);
          const int bb = row >> 11, ss = row & 2047;
          const int hh = col2 >> 7, dd = col2 & 127;
          *(uint64_t*)&Vt[((size_t)((bb << 4) + hh) * 128 + dd) * 2048 + ss] = pk.q;
        }
      }
    }
  }
}

// ---------------- RoPE in-place, fused Q+K ----------------
__global__ __launch_bounds__(256) void rope_qk(u16* __restrict__ Qb, u16* __restrict__ Kb,
                                               const int* __restrict__ pos) {
  int p = blockIdx.x * 256 + threadIdx.x;
  u16* X = (p >> 22) ? Kb : Qb;
  int pp = p & 4194303;
  int m = pp >> 10, j2 = pp & 1023;
  int h = j2 >> 6, j = j2 & 63;
  int s = m & (SEQQ - 1);
  float fp = (float)pos[s];
  float freq = exp2f((float)j * -0.20762050593046014f);
  float ang = fp * freq;
  float sn, cs;
  sincosf(ang, &sn, &cs);
  u16* px = X + (size_t)m * D_MODEL + h * DK + 2 * j;
  uint32_t pair = *(uint32_t*)px;
  float x1 = b2f((u16)(pair & 0xffff)), x2 = b2f((u16)(pair >> 16));
  u16 r1 = f2b(x1 * cs - x2 * sn);
  u16 r2 = f2b(x1 * sn + x2 * cs);
  *(uint32_t*)px = (uint32_t)r1 | ((uint32_t)r2 << 16);
}

// ---------------- Flash attention (causal), swapped-QK^T in-register softmax ----------------
__global__ __launch_bounds__(256) void attn_fwd(const u16* __restrict__ Q,
                                                const u16* __restrict__ Kg,
                                                const u16* __restrict__ Vt,
                                                u16* __restrict__ O) {
  __shared__ __align__(16) u16 Klds[2][64 * 128];
  __shared__ __align__(16) u16 Vlds[2][128 * 64];
  const int tid = threadIdx.x, wave = tid >> 6, lane = tid & 63;
  const int l31 = lane & 31, l5 = lane >> 5;
  const int bh = blockIdx.x;
  const int bxr = 15 - (int)blockIdx.y;
  const int b = bh >> 4, h = bh & 15;
  const int q0 = bxr * 128, qw = q0 + wave * 32;
  const float qscale = 0.1275174470974136f;      // 1/sqrt(128)*log2(e)

  short8 bq[8];
  {
    const u16* Qp = Q + (size_t)(b * SEQQ + qw + l31) * D_MODEL + h * DK + l5 * 8;
#pragma unroll
    for (int dt = 0; dt < 8; ++dt) {
      short8 raw = *(const short8*)(Qp + dt * 16);
#pragma unroll
      for (int j = 0; j < 8; ++j) raw[j] = (short)f2b(b2f((u16)raw[j]) * qscale);
      bq[dt] = raw;
    }
  }
  asm volatile("s_waitcnt vmcnt(0)" ::: "memory");

  f32x16 facc[4] = {};
  float mrun = -1e30f, lpart = 0.f;

  const u16* Kbase = Kg + (size_t)b * SEQQ * D_MODEL + h * DK;
  const u16* Vbase = Vt + (size_t)bh * DK * SEQQ;
  const u16* ksrc[4]; const u16* vsrc[4];
#pragma unroll
  for (int g = 0; g < 4; ++g) {
    int kr = g * 16 + (tid >> 4);
    int kc = ((tid & 15) * 8) ^ ((kr & 7) << 3);
    ksrc[g] = Kbase + (size_t)kr * D_MODEL + kc;
    int vr = g * 32 + (tid >> 3);
    int vc = ((tid & 7) * 8) ^ ((vr & 7) << 3);
    vsrc[g] = Vbase + (size_t)vr * SEQQ + vc;
  }
  const int dstoff = tid * 8;
  const int nkt = 2 * (bxr + 1);

#pragma unroll
  for (int g = 0; g < 4; ++g) { gload_lds16(ksrc[g], &Klds[0][g * 2048 + dstoff]); ksrc[g] += (size_t)64 * D_MODEL; }
#pragma unroll
  for (int g = 0; g < 4; ++g) { gload_lds16(vsrc[g], &Vlds[0][g * 2048 + dstoff]); vsrc[g] += 64; }

  for (int kt = 0; kt < nkt; ++kt) {
    const int k0 = kt * 64, cur = kt & 1;
    asm volatile("s_waitcnt vmcnt(0)" ::: "memory");
    BARRIER();
    if (kt + 1 < nkt) {
#pragma unroll
      for (int g = 0; g < 4; ++g) { gload_lds16(ksrc[g], &Klds[cur ^ 1][g * 2048 + dstoff]); ksrc[g] += (size_t)64 * D_MODEL; }
#pragma unroll
      for (int g = 0; g < 4; ++g) { gload_lds16(vsrc[g], &Vlds[cur ^ 1][g * 2048 + dstoff]); vsrc[g] += 64; }
    }
    if (k0 > qw + 31) continue;

    const u16* Kl = Klds[cur];
    const u16* Vl = Vlds[cur];

    f32x16 st0 = {}, st1 = {};
    __builtin_amdgcn_s_setprio(1);
#pragma unroll
    for (int dt = 0; dt < 8; ++dt) {
      const int ch = ((2 * dt + l5) ^ (l31 & 7)) * 8;
      short8 ak0 = *(const short8*)&Kl[l31 * 128 + ch];
      short8 ak1 = *(const short8*)&Kl[(32 + l31) * 128 + ch];
      st0 = __builtin_amdgcn_mfma_f32_32x32x16_bf16(ak0, bq[dt], st0, 0, 0, 0);
      st1 = __builtin_amdgcn_mfma_f32_32x32x16_bf16(ak1, bq[dt], st1, 0, 0, 0);
    }
    __builtin_amdgcn_s_setprio(0);

    if (k0 + 63 > qw) {
      const int qm = qw + l31 - k0 - 4 * l5;
#pragma unroll
      for (int r = 0; r < 16; ++r) {
        const int kc0 = (r & 3) + 8 * (r >> 2);
        st0[r] = (kc0 > qm) ? -1e30f : st0[r];
        st1[r] = (kc0 + 32 > qm) ? -1e30f : st1[r];
      }
    }

    float mx[8];
#pragma unroll
    for (int r = 0; r < 8; ++r) mx[r] = fmaxf(fmaxf(st0[r], st0[r + 8]), fmaxf(st1[r], st1[r + 8]));
    float m = fmaxf(fmaxf(fmaxf(mx[0], mx[1]), fmaxf(mx[2], mx[3])),
                    fmaxf(fmaxf(mx[4], mx[5]), fmaxf(mx[6], mx[7])));
    {
      uint2v sw = __builtin_amdgcn_permlane32_swap(__float_as_uint(m), __float_as_uint(m), false, false);
      m = fmaxf(__uint_as_float(sw.x), __uint_as_float(sw.y));
    }
    const float mn = fmaxf(mrun, m);
    const float al = exp2f(mrun - mn);
    mrun = mn;
    float ps = 0.f;
#pragma unroll
    for (int r = 0; r < 16; ++r) { float p = exp2f(st0[r] - mn); st0[r] = p; ps += p; }
#pragma unroll
    for (int r = 0; r < 16; ++r) { float p = exp2f(st1[r] - mn); st1[r] = p; ps += p; }
    lpart = lpart * al + ps;
#pragma unroll
    for (int db = 0; db < 4; ++db) facc[db] *= al;

    short8 pa[4];
#pragma unroll
    for (int ks2 = 0; ks2 < 2; ++ks2) {
#pragma unroll
      for (int t0 = 0; t0 < 2; ++t0) {
        uint32_t c0w0, c0w1, c1w0, c1w1;
        if (ks2 == 0) {
          asm("v_cvt_pk_bf16_f32 %0, %1, %2" : "=v"(c0w0) : "v"(st0[8 * t0 + 0]), "v"(st0[8 * t0 + 1]));
          asm("v_cvt_pk_bf16_f32 %0, %1, %2" : "=v"(c0w1) : "v"(st0[8 * t0 + 2]), "v"(st0[8 * t0 + 3]));
          asm("v_cvt_pk_bf16_f32 %0, %1, %2" : "=v"(c1w0) : "v"(st0[8 * t0 + 4]), "v"(st0[8 * t0 + 5]));
          asm("v_cvt_pk_bf16_f32 %0, %1, %2" : "=v"(c1w1) : "v"(st0[8 * t0 + 6]), "v"(st0[8 * t0 + 7]));
        } else {
          asm("v_cvt_pk_bf16_f32 %0, %1, %2" : "=v"(c0w0) : "v"(st1[8 * t0 + 0]), "v"(st1[8 * t0 + 1]));
          asm("v_cvt_pk_bf16_f32 %0, %1, %2" : "=v"(c0w1) : "v"(st1[8 * t0 + 2]), "v"(st1[8 * t0 + 3]));
          asm("v_cvt_pk_bf16_f32 %0, %1, %2" : "=v"(c1w0) : "v"(st1[8 * t0 + 4]), "v"(st1[8 * t0 + 5]));
          asm("v_cvt_pk_bf16_f32 %0, %1, %2" : "=v"(c1w1) : "v"(st1[8 * t0 + 6]), "v"(st1[8 * t0 + 7]));
        }
        uint2v s0 = __builtin_amdgcn_permlane32_swap(c0w0, c1w0, false, false);
        uint2v s1 = __builtin_amdgcn_permlane32_swap(c0w1, c1w1, false, false);
        union { uint32_t w[4]; short8 v; } u;
        u.w[0] = s0.x; u.w[1] = s1.x; u.w[2] = s0.y; u.w[3] = s1.y;
        pa[2 * ks2 + t0] = u.v;
      }
    }

    __builtin_amdgcn_s_setprio(1);
#pragma unroll
    for (int db = 0; db < 4; ++db) {
      const int row = 32 * db + l31;
#pragma unroll
      for (int t = 0; t < 4; ++t) {
        const int ch = ((2 * t + l5) ^ (l31 & 7)) * 8;
        short8 av = *(const short8*)&Vl[row * 64 + ch];
        facc[db] = __builtin_amdgcn_mfma_f32_32x32x16_bf16(av, pa[t], facc[db], 0, 0, 0);
      }
    }
    __builtin_amdgcn_s_setprio(0);
  }

  float inv;
  {
    uint2v sw = __builtin_amdgcn_permlane32_swap(__float_as_uint(lpart), __float_as_uint(lpart), false, false);
    inv = 1.0f / (__uint_as_float(sw.x) + __uint_as_float(sw.y));
  }
  u16* Op = O + (size_t)(b * SEQQ + qw + l31) * D_MODEL + h * DK;
#pragma unroll
  for (int db = 0; db < 4; ++db)
#pragma unroll
    for (int a = 0; a < 4; ++a) {
      union { u16 h4[4]; uint64_t q; } pk;
#pragma unroll
      for (int c = 0; c < 4; ++c) pk.h4[c] = f2b(facc[db][4 * a + c] * inv);
      *(uint64_t*)&Op[32 * db + 8 * a + 4 * l5] = pk.q;
    }
}

extern "C" void kernel_launch(void* const* d_in, const int* in_sizes, int n_in,
                              void* d_out, int out_size, void* d_ws, size_t ws_size,
                              hipStream_t stream) {
  const float* x   = (const float*)d_in[0];
  const int*   pos = (const int*)d_in[1];
  const float* wq  = (const float*)d_in[2];
  const float* wk  = (const float*)d_in[3];
  const float* wv  = (const float*)d_in[4];
  const float* wo  = (const float*)d_in[5];
  float* out = (float*)d_out;
  char* ws = (char*)d_ws;

  u16* Xb   = (u16*)(ws);
  u16* Wqkv = (u16*)(ws + (16u << 20));
  u16* Wob  = (u16*)(ws + (40u << 20));
  u16* Qb   = (u16*)(ws + (48u << 20));
  u16* Kb   = (u16*)(ws + (64u << 20));
  u16* Vt   = (u16*)(ws + (80u << 20));
  u16* AO   = Xb;

  const int nX = MTOT * D_MODEL;

  cvt_bf16<<<nX / 1024, 256, 0, stream>>>(x, Xb, nX / 4);
  cvt_w<<<16384, 256, 0, stream>>>(wq, wk, wv, wo, Wqkv, Wob);

  // fused QKV GEMM: 128x192 tiles, grid 32x32 = 1024 (4 exact rounds, 2 blocks/CU)
  gemmT<4, 3, 0><<<1024, 512, 0, stream>>>(Xb, Wqkv, Qb, Kb, Vt, nullptr, 32, 128);

  rope_qk<<<32768, 256, 0, stream>>>(Qb, Kb, pos);

  attn_fwd<<<dim3(BATCH * NHEAD, SEQQ / 128), 256, 0, stream>>>(Qb, Kb, Vt, AO);

  // final GEMM: 128x256 tiles, grid 32x8 = 256 (1 exact round), f32 out
  gemmT<4, 4, 1><<<256, 512, 0, stream>>>(AO, Wob, nullptr, nullptr, nullptr, out, 32, 32);
}